// Round 10
// baseline (295.869 us; speedup 1.0000x reference)
//
#include <hip/hip_runtime.h>

// ---------------------------------------------------------------------------
// LocallyConnectedNN: x[16384,256] -> conv3x3(1->16)+BN+ReLU -> conv2x2(16->32)
// +BN+ReLU -> conv1x1(32->64)+BN+ReLU -> FC(10816->10).
// Round 18: (1) ADAPTIVE a1 cache -- round 17's fixed 300MB guard never fired
// (ws < 300MB). Host computes cached = clamp((ws_size - a1off)/7168, 0,
// 16384) & ~15; k3 stores a1 rows for blocks < cached/16; k5 branches
// per-block (uniform) between a1g-register-load path (conv1 deleted) and the
// proven recompute path. (2) pkbf = single v_cvt_pk_bf16_f32 (inline asm,
// RTNE) replacing the 3-op add+add+perm pack everywhere (k1/k3/k5/k7) --
// ~2 VALU saved per pack, ~20/120 issues per k5 row. Numerics: RTNE vs
// half-up differs on exact ties only.
// ---------------------------------------------------------------------------

#define NPART 1024
#define P2_OFF 32768      // [1024][64] conv2 stats partials
#define ST_OFF 229376     // s1[16] t1[16] s2[32] t2[32] s3[64] t3[64]
#define ST1 ST_OFF
#define ST2 (ST_OFF + 32)
#define ST3 (ST_OFF + 96)
#define C2R_OFF 230400    // reduced [768 C2 tiles | 32 S2]
#define C1R_OFF 231424    // reduced x-patch Cext [16x16]
#define C2P_OFF 262144    // block partials (1MB..): k1 [1024][256], k5 [1024][800]
#define A2G_BYTE 5242880ull // a2 cache: [img][13 i][13 pix][32 ch] bf16, 177MB
#define FCB_N 86528       // fcB u32: [169 p][2 h][64 lane][4 u]
#define A1S 24            // a1h LDS row stride (shorts)
#define A1B 384           // one a1 LDS buffer (16 rows x A1S)

typedef __attribute__((ext_vector_type(8))) short bf16x8;
typedef __attribute__((ext_vector_type(4))) float f32x4;
typedef __attribute__((ext_vector_type(4))) unsigned int u32x4;

__device__ __forceinline__ unsigned int f2bf(float f) {
  unsigned int u = __float_as_uint(f);
  return (u + 0x7fffu + ((u >> 16) & 1u)) >> 16;   // RTNE bf16 bits
}
// pack two floats to bf16x2: ONE v_cvt_pk_bf16_f32 (RTNE), lo=a hi=b
__device__ __forceinline__ unsigned int pkbf(float a, float b) {
  unsigned int r;
  asm("v_cvt_pk_bf16_f32 %0, %1, %2" : "=v"(r) : "v"(a), "v"(b));
  return r;
}
__device__ __forceinline__ bf16x8 mkfrag(uint2 a, uint2 b) {
  u32x4 u = {a.x, a.y, b.x, b.y};
  return __builtin_bit_cast(bf16x8, u);
}

// conv1 (3x3,1->16)+bn1(folded)+relu for output row r, swapped operands:
// A = w1*rs1 (m=ch), B = im2row (n=col j), C-init = rt1.
// D: col(lane&15)=j, row(4q+r)=ch -> dst[j][ch] write = 1 ds_write_b64.
__device__ __forceinline__ void conv1_mfma(
    const float* __restrict__ sxi,   // [256] image (+finite pad after)
    short* dst,                      // one row buffer [16 j][A1S ch]
    int r, int b, int q, bf16x8 a1f, f32x4 c1i)
{
  bf16x8 bf = {0, 0, 0, 0, 0, 0, 0, 0};
  unsigned* bu = (unsigned*)&bf;
  if (q == 0) {
    bu[0] = pkbf(sxi[r * 16 + b],           sxi[r * 16 + b + 1]);
    bu[1] = pkbf(sxi[r * 16 + b + 2],       sxi[(r + 1) * 16 + b]);
    bu[2] = pkbf(sxi[(r + 1) * 16 + b + 1], sxi[(r + 1) * 16 + b + 2]);
    bu[3] = pkbf(sxi[(r + 2) * 16 + b],     sxi[(r + 2) * 16 + b + 1]);
  } else if (q == 1) {
    bu[0] = pkbf(sxi[(r + 2) * 16 + b + 2], 0.f);
  }
  f32x4 acc = c1i;
  acc = __builtin_amdgcn_mfma_f32_16x16x32_bf16(a1f, bf, acc, 0, 0, 0);
  float v0 = acc[0] > 0.f ? acc[0] : 0.f;
  float v1 = acc[1] > 0.f ? acc[1] : 0.f;
  float v2 = acc[2] > 0.f ? acc[2] : 0.f;
  float v3 = acc[3] > 0.f ? acc[3] : 0.f;
  uint2 pk;
  pk.x = pkbf(v0, v1);
  pk.y = pkbf(v2, v3);
  *(uint2*)(dst + b * A1S + 4 * q) = pk;
}

// conv1 A-frag: m=ch=b, k=tap 8q+j (zeros for tap>=9), scaled by rs1[b].
__device__ __forceinline__ bf16x8 conv1_afrag(const float* w1, float rs1b,
                                              int b, int q) {
  bf16x8 v;
#pragma unroll
  for (int j = 0; j < 8; ++j) {
    int tap = 8 * q + j;
    v[j] = (tap < 9) ? (short)f2bf(w1[b * 9 + tap] * rs1b) : (short)0;
  }
  return v;
}

// Shared k5 inner step: conv2 MFMAs + relu + pack + stage + burst + syrk.
struct SyrkAcc { f32x4 T0, T1, T2, S0, S1; };
__device__ __forceinline__ void conv2_step(
    bf16x8 ah0, bf16x8 ah1, const bf16x8* b2h, const f32x4* c2i,
    short* st, short* gb, int i, int b, int q, int lane,
    uint2* pkp, SyrkAcc& A, bf16x8 ones)
{
  uint2 pkc[2];
#pragma unroll
  for (int nt = 0; nt < 2; ++nt) {
    f32x4 acc2 = c2i[nt];
    acc2 = __builtin_amdgcn_mfma_f32_16x16x32_bf16(ah0, b2h[nt], acc2, 0, 0, 0);
    acc2 = __builtin_amdgcn_mfma_f32_16x16x32_bf16(ah1, b2h[2 + nt], acc2, 0, 0, 0);
    float v0 = acc2[0] > 0.f ? acc2[0] : 0.f;
    float v1 = acc2[1] > 0.f ? acc2[1] : 0.f;
    float v2 = acc2[2] > 0.f ? acc2[2] : 0.f;
    float v3 = acc2[3] > 0.f ? acc2[3] : 0.f;
    uint2 pk;
    pk.x = pkbf(v0, v1);
    pk.y = pkbf(v2, v3);
    short* sp = st + nt * 16 + b;
    sp[(4 * q + 0) * 32] = (short)pk.x;
    sp[(4 * q + 1) * 32] = (short)(pk.x >> 16);
    sp[(4 * q + 2) * 32] = (short)pk.y;
    sp[(4 * q + 3) * 32] = (short)(pk.y >> 16);
    pkc[nt] = pk;
  }
  __builtin_amdgcn_wave_barrier();
  if (lane < 52) {   // one coalesced 832B burst: 13 pix x 32 ch
    bf16x8 vv = *(const bf16x8*)(st + lane * 8);
    *(bf16x8*)(gb + (size_t)i * 416 + lane * 8) = vv;
  }
  if (i & 1) {       // syrk over row pair (i-1, i), frags from registers
    bf16x8 xf0 = mkfrag(pkp[0], pkc[0]);
    bf16x8 xf1 = mkfrag(pkp[1], pkc[1]);
    A.T0 = __builtin_amdgcn_mfma_f32_16x16x32_bf16(xf0, xf0, A.T0, 0, 0, 0);
    A.T1 = __builtin_amdgcn_mfma_f32_16x16x32_bf16(xf0, xf1, A.T1, 0, 0, 0);
    A.T2 = __builtin_amdgcn_mfma_f32_16x16x32_bf16(xf1, xf1, A.T2, 0, 0, 0);
    A.S0 = __builtin_amdgcn_mfma_f32_16x16x32_bf16(ones, xf0, A.S0, 0, 0, 0);
    A.S1 = __builtin_amdgcn_mfma_f32_16x16x32_bf16(ones, xf1, A.S1, 0, 0, 0);
  } else {
    pkp[0] = pkc[0];
    pkp[1] = pkc[1];
  }
  __builtin_amdgcn_wave_barrier();
}
__device__ __forceinline__ void syrk_tail(uint2* pkp, SyrkAcc& A, bf16x8 ones) {
  uint2 zz; zz.x = 0u; zz.y = 0u;
  bf16x8 xf0 = mkfrag(pkp[0], zz);
  bf16x8 xf1 = mkfrag(pkp[1], zz);
  A.T0 = __builtin_amdgcn_mfma_f32_16x16x32_bf16(xf0, xf0, A.T0, 0, 0, 0);
  A.T1 = __builtin_amdgcn_mfma_f32_16x16x32_bf16(xf0, xf1, A.T1, 0, 0, 0);
  A.T2 = __builtin_amdgcn_mfma_f32_16x16x32_bf16(xf1, xf1, A.T2, 0, 0, 0);
  A.S0 = __builtin_amdgcn_mfma_f32_16x16x32_bf16(ones, xf0, A.S0, 0, 0, 0);
  A.S1 = __builtin_amdgcn_mfma_f32_16x16x32_bf16(ones, xf1, A.S1, 0, 0, 0);
}

// K1: x patch-covariance via MFMA syrk. x pre-packed to bf16 in LDS with TWO
// column-shifted copies: sb[img][row][cp][16 cols], cp=1 shifted by +1 col.
__global__ __launch_bounds__(256) void k1_xsyrk(
    const float* __restrict__ x, float* __restrict__ parts)
{
  __shared__ alignas(16) short sb[16 * 16 * 2 * 16];  // 16KB
  const int tid = threadIdx.x, w = tid >> 6, lane = tid & 63;
  const int b = lane & 15, q = lane >> 4;
  // phase 1: load f32x4, pack copy0 (all 16 real cols)
  {
    const float4* xs = (const float4*)(x + (size_t)blockIdx.x * (16 * 256));
    for (int e = tid; e < 16 * 64; e += 256) {
      float4 v = xs[e];
      int img = e >> 6, row = (e >> 2) & 15, g = e & 3;
      uint2 pk;
      pk.x = pkbf(v.x, v.y);
      pk.y = pkbf(v.z, v.w);
      *(uint2*)(sb + ((img * 16 + row) * 2 + 0) * 16 + 4 * g) = pk;
    }
  }
  __syncthreads();
  // phase 2: copy1 = copy0 shifted by one column (col 16 -> 0)
  {
    int img = tid >> 4, row = tid & 15;
    const unsigned* s0 = (const unsigned*)(sb + ((img * 16 + row) * 2 + 0) * 16);
    unsigned* s1 = (unsigned*)(sb + ((img * 16 + row) * 2 + 1) * 16);
    unsigned wprev = s0[0];
#pragma unroll
    for (int c = 0; c < 8; ++c) {
      unsigned wnext = (c < 7) ? s0[c + 1] : 0u;
      s1[c] = __builtin_amdgcn_perm(wnext, wprev, 0x05040302u);
      wprev = wnext;
    }
  }
  __syncthreads();
  const int di = (b < 9) ? (b / 3) : 0;
  const int dj = (b < 9) ? (b - di * 3) : 0;
  const int cp = dj & 1, dsh = dj >> 1;
  const int h = q >> 1, jb = (q & 1) * 8;
  const int wb = (jb >> 1) + dsh;
  f32x4 acc = {0.f, 0.f, 0.f, 0.f};
#pragma unroll 1
  for (int t = 0; t < 4; ++t) {
    const int ib = (w * 4 + t) * 16;
#pragma unroll 1
    for (int s = 0; s < 7; ++s) {
      bf16x8 af;
      unsigned* au = (unsigned*)&af;
      if (b < 9) {
        const unsigned* sr = (const unsigned*)(
            sb + ((ib + (2 * s + h + di)) * 2 + cp) * 16);
        au[0] = sr[wb];
        au[1] = sr[wb + 1];
        au[2] = sr[wb + 2];
        au[3] = (jb == 0) ? sr[wb + 3] : 0u;   // out-col >= 14 -> zero slot
      } else if (b == 9) {
#pragma unroll
        for (int cc = 0; cc < 4; ++cc) {
          unsigned lo = (jb + 2 * cc     < 14) ? 0x3F80u : 0u;
          unsigned hi = (jb + 2 * cc + 1 < 14) ? 0x3F800000u : 0u;
          au[cc] = lo | hi;
        }
      } else {
#pragma unroll
        for (int cc = 0; cc < 4; ++cc) au[cc] = 0u;
      }
      acc = __builtin_amdgcn_mfma_f32_16x16x32_bf16(af, af, acc, 0, 0, 0);
    }
  }
  __syncthreads();                 // done reading sb; reuse as reduce buffer
  float* redc = (float*)sb;
#pragma unroll
  for (int rr = 0; rr < 4; ++rr)
    redc[w * 256 + (4 * q + rr) * 16 + b] = acc[rr];
  __syncthreads();
  parts[blockIdx.x * 256 + tid] =
      redc[tid] + redc[256 + tid] + redc[512 + tid] + redc[768 + tid];
}

// Reduce k1 partials [1024][256] -> Cext[256].
__global__ __launch_bounds__(256) void k_stats1a(
    const float* __restrict__ parts, float* __restrict__ ws)
{
  const int e = blockIdx.x, tid = threadIdx.x;
  const int w = tid >> 6, lane = tid & 63;
  __shared__ float rs[4];
  float s = 0.f;
#pragma unroll 4
  for (int i = tid; i < 1024; i += 256) s += parts[i * 256 + e];
#pragma unroll
  for (int d = 1; d < 64; d <<= 1) s += __shfl_xor(s, d);
  if (lane == 0) rs[w] = s;
  __syncthreads();
  if (tid == 0) ws[C1R_OFF + e] = rs[0] + rs[1] + rs[2] + rs[3];
}

// BN1 finalize from Cext: mean = w^T S /N, E[y^2] = w^T C w /N.
__global__ __launch_bounds__(64) void k_stats1b(
    const float* __restrict__ w1, const float* __restrict__ gamma,
    const float* __restrict__ beta, float* __restrict__ ws)
{
  const int c = threadIdx.x;
  if (c >= 16) return;
  const float* C = ws + C1R_OFF;
  float wr[9];
#pragma unroll
  for (int p = 0; p < 9; ++p) wr[p] = w1[c * 9 + p];
  float msum = 0.f;
#pragma unroll
  for (int p = 0; p < 9; ++p) msum += wr[p] * C[9 * 16 + p];
  float e2 = 0.f;
#pragma unroll
  for (int a = 0; a < 9; ++a)
#pragma unroll
    for (int bb = 0; bb < 9; ++bb)
      e2 += wr[a] * wr[bb] * C[a * 16 + bb];
  const float inv_n = 1.0f / (16384.0f * 196.0f);
  float mean = msum * inv_n;
  float var  = e2 * inv_n - mean * mean;
  float sv   = gamma[c] * rsqrtf(var + 1e-5f);
  ws[ST1 + c]      = sv;
  ws[ST1 + 16 + c] = beta[c] - mean * sv;
}

// BN2 finalize, one block per channel (reduces P2 [1024][64]).
__global__ __launch_bounds__(256) void k_stats2(
    const float* __restrict__ gamma, const float* __restrict__ beta,
    float* __restrict__ ws, int nch, int part_off, int st_off, float inv_n)
{
  const int c = blockIdx.x, tid = threadIdx.x;
  const int w = tid >> 6, lane = tid & 63;
  __shared__ float rs[4], rq[4];
  float s = 0.f, q = 0.f;
#pragma unroll 4
  for (int i = tid; i < NPART; i += 256) {
    s += ws[part_off + i * 2 * nch + c];
    q += ws[part_off + i * 2 * nch + nch + c];
  }
#pragma unroll
  for (int d = 1; d < 64; d <<= 1) {
    s += __shfl_xor(s, d);
    q += __shfl_xor(q, d);
  }
  if (lane == 0) { rs[w] = s; rq[w] = q; }
  __syncthreads();
  if (tid == 0) {
    float st = rs[0] + rs[1] + rs[2] + rs[3];
    float qt = rq[0] + rq[1] + rq[2] + rq[3];
    float mean = st * inv_n;
    float var  = qt * inv_n - mean * mean;
    float sv   = gamma[c] * rsqrtf(var + 1e-5f);
    ws[st_off + c]       = sv;
    ws[st_off + nch + c] = beta[c] - mean * sv;
  }
}

// K3: conv1(MFMA,folded,depth-2 pipeline) + conv2(swapped, raw) stats.
// Stores a1 rows to a1g for blocks < cached/16 (one 512B store per row).
__global__ __launch_bounds__(256) void k3_v2(
    const float* __restrict__ x, const float* __restrict__ w1,
    const float* __restrict__ w2, float* __restrict__ ws,
    short* __restrict__ a1g, int cached)
{
  __shared__ float sx_s[16 * 256 + 16];
  __shared__ alignas(16) short a1h[4 * 3 * A1B];
  __shared__ float redf[256];
  const int tid = threadIdx.x, w = tid >> 6, lane = tid & 63;
  const int b = lane & 15, q = lane >> 4;
  const bool doStore = (int)blockIdx.x < (cached >> 4);
  {
    const float4* xs = (const float4*)(x + (size_t)blockIdx.x * (16 * 256));
    float4* sd = (float4*)sx_s;
    for (int e = tid; e < 16 * 64; e += 256) sd[e] = xs[e];
    if (tid < 16) sx_s[16 * 256 + tid] = 0.f;
  }
  bf16x8 a1f = conv1_afrag(w1, ws[ST1 + b], b, q);
  f32x4 c1i;
#pragma unroll
  for (int r = 0; r < 4; ++r) c1i[r] = ws[ST1 + 16 + 4 * q + r];
  bf16x8 b2h[4];   // A-side: [ks][nt], m=ch=b, raw
#pragma unroll
  for (int ks = 0; ks < 2; ++ks)
#pragma unroll
    for (int nt = 0; nt < 2; ++nt) {
      bf16x8 vh;
#pragma unroll
      for (int j = 0; j < 8; ++j) {
        int kk = 8 * (q & 1) + j, dj = q >> 1;
        vh[j] = (short)f2bf(w2[(nt * 16 + b) * 64 + kk * 4 + ks * 2 + dj]);
      }
      b2h[ks * 2 + nt] = vh;
    }
  const float vb = (b < 13) ? 1.f : 0.f;
  const int colAr = (b + (q >> 1) < 15) ? (b + (q >> 1)) : 15;
  const int offAl = colAr * A1S + 8 * (q & 1);
  const int sco = (lane >> 1) * A1S + (lane & 1) * 8;  // LDS src for store
  __syncthreads();

  float s2r[2][4] = {{0.f,0.f,0.f,0.f},{0.f,0.f,0.f,0.f}};
  float q2r[2][4] = {{0.f,0.f,0.f,0.f},{0.f,0.f,0.f,0.f}};
  short* pb0 = a1h + w * (3 * A1B);
  short* pb1 = pb0 + A1B;
  short* pb2 = pb0 + 2 * A1B;
#pragma unroll 1
  for (int t = 0; t < 4; ++t) {
    const int img = blockIdx.x * 16 + w * 4 + t;
    short* ag = a1g + (size_t)img * 3584;
    const float* sxi = sx_s + (w * 4 + t) * 256;
    conv1_mfma(sxi, pb0, 0, b, q, a1f, c1i);
    conv1_mfma(sxi, pb1, 1, b, q, a1f, c1i);
    __builtin_amdgcn_wave_barrier();
    if (doStore && lane < 32) {
      *(bf16x8*)(ag + 0 * 256 + lane * 8) = *(const bf16x8*)(pb0 + sco);
      *(bf16x8*)(ag + 1 * 256 + lane * 8) = *(const bf16x8*)(pb1 + sco);
    }
#pragma unroll 1
    for (int i = 0; i < 13; ++i) {
      if (i < 12) {
        conv1_mfma(sxi, pb2, i + 2, b, q, a1f, c1i);
        __builtin_amdgcn_wave_barrier();
        if (doStore && lane < 32)
          *(bf16x8*)(ag + (size_t)(i + 2) * 256 + lane * 8) =
              *(const bf16x8*)(pb2 + sco);
      }
      bf16x8 ah0 = *(const bf16x8*)(pb0 + offAl);
      bf16x8 ah1 = *(const bf16x8*)(pb1 + offAl);
      f32x4 acc2[2] = {{0.f,0.f,0.f,0.f},{0.f,0.f,0.f,0.f}};
#pragma unroll
      for (int nt = 0; nt < 2; ++nt) {
        acc2[nt] = __builtin_amdgcn_mfma_f32_16x16x32_bf16(b2h[nt], ah0, acc2[nt], 0, 0, 0);
        acc2[nt] = __builtin_amdgcn_mfma_f32_16x16x32_bf16(b2h[2 + nt], ah1, acc2[nt], 0, 0, 0);
      }
#pragma unroll
      for (int nt = 0; nt < 2; ++nt)
#pragma unroll
        for (int r = 0; r < 4; ++r) {
          float ym = acc2[nt][r] * vb;
          s2r[nt][r] += ym;
          q2r[nt][r] = fmaf(ym, acc2[nt][r], q2r[nt][r]);
        }
      short* tpb = pb0; pb0 = pb1; pb1 = pb2; pb2 = tpb;
      __builtin_amdgcn_wave_barrier();
    }
  }
  // reduce over the 16 pix-lanes (b); lane b==0 holds ch = nt*16+4q+r
#pragma unroll
  for (int nt = 0; nt < 2; ++nt)
#pragma unroll
    for (int r = 0; r < 4; ++r) {
      float sv = s2r[nt][r], qv = q2r[nt][r];
      sv += __shfl_xor(sv, 1); sv += __shfl_xor(sv, 2);
      sv += __shfl_xor(sv, 4); sv += __shfl_xor(sv, 8);
      qv += __shfl_xor(qv, 1); qv += __shfl_xor(qv, 2);
      qv += __shfl_xor(qv, 4); qv += __shfl_xor(qv, 8);
      if (b == 0) {
        redf[w * 64 + nt * 16 + 4 * q + r]      = sv;
        redf[w * 64 + 32 + nt * 16 + 4 * q + r] = qv;
      }
    }
  __syncthreads();
  if (tid < 64)
    ws[P2_OFF + blockIdx.x * 64 + tid] =
        redf[tid] + redf[64 + tid] + redf[128 + tid] + redf[192 + tid];
}

// K5: conv2(UN-swapped, bn2-folded) -> a2 + BN3 syrk. Per-block branch:
// cached blocks load ah frags straight from a1g (conv1 deleted, depth-2
// register prefetch); others recompute conv1 (proven path).
__global__ __launch_bounds__(256) void k5_v2(
    const float* __restrict__ x, const float* __restrict__ w1,
    const short* __restrict__ a1g, const float* __restrict__ w2,
    float* __restrict__ ws, short* __restrict__ a2g,
    float* __restrict__ parts, int cached)
{
  __shared__ float sx_s[16 * 256 + 16];          // reused as redc at the end
  __shared__ alignas(16) short a1h[4 * 3 * A1B];
  __shared__ alignas(16) short a2st[4 * 512];    // per-wave [16pix][32ch]
  __shared__ float s2red[4 * 32];
  const int tid = threadIdx.x, w = tid >> 6, lane = tid & 63;
  const int b = lane & 15, q = lane >> 4;
  const bool useCache = (int)blockIdx.x < (cached >> 4);
  if (!useCache) {
    const float4* xs = (const float4*)(x + (size_t)blockIdx.x * (16 * 256));
    float4* sd = (float4*)sx_s;
    for (int e = tid; e < 16 * 64; e += 256) sd[e] = xs[e];
    if (tid < 16) sx_s[16 * 256 + tid] = 0.f;
  }
  bf16x8 a1f = {0,0,0,0,0,0,0,0};
  f32x4 c1i = {0.f, 0.f, 0.f, 0.f};
  if (!useCache) {
    a1f = conv1_afrag(w1, ws[ST1 + b], b, q);
#pragma unroll
    for (int r = 0; r < 4; ++r) c1i[r] = ws[ST1 + 16 + 4 * q + r];
  }
  bf16x8 b2h[4];   // B-side: [ks][nt], n=ch=b, scaled by s2[nt*16+b]
#pragma unroll
  for (int ks = 0; ks < 2; ++ks)
#pragma unroll
    for (int nt = 0; nt < 2; ++nt) {
      float rs2b = ws[ST2 + nt * 16 + b];
      bf16x8 vh;
#pragma unroll
      for (int j = 0; j < 8; ++j) {
        int kk = 8 * (q & 1) + j, dj = q >> 1;
        vh[j] = (short)f2bf(w2[(nt * 16 + b) * 64 + kk * 4 + ks * 2 + dj] * rs2b);
      }
      b2h[ks * 2 + nt] = vh;
    }
  // C-init: D rows are PIXELS (mask 4q+r>=13), bias t2 indexed by CH=nt*16+b.
  f32x4 c2i[2];
#pragma unroll
  for (int nt = 0; nt < 2; ++nt) {
    float t2b = ws[ST2 + 32 + nt * 16 + b];
#pragma unroll
    for (int r = 0; r < 4; ++r)
      c2i[nt][r] = (4 * q + r < 13) ? t2b : -1e30f;
  }
  const int colAr = (b + (q >> 1) < 15) ? (b + (q >> 1)) : 15;
  const int offAl = colAr * A1S + 8 * (q & 1);
  const int loff  = colAr * 16  + (q & 1) * 8;   // shorts within a1g 512B row
  const u32x4 ou = {0x3F803F80u, 0x3F803F80u, 0x3F803F80u, 0x3F803F80u};
  const bf16x8 ones = __builtin_bit_cast(bf16x8, ou);
  __syncthreads();

  SyrkAcc A;
  A.T0 = A.T1 = A.T2 = A.S0 = A.S1 = (f32x4){0.f, 0.f, 0.f, 0.f};
  short* st = a2st + w * 512;
  if (useCache) {
#pragma unroll 1
    for (int t = 0; t < 4; ++t) {
      const int img = blockIdx.x * 16 + w * 4 + t;
      const short* ag = a1g + (size_t)img * 3584 + loff;
      short* gb = a2g + (size_t)img * 5408;
      bf16x8 rA = *(const bf16x8*)(ag);
      bf16x8 rB = *(const bf16x8*)(ag + 256);
      bf16x8 rC = *(const bf16x8*)(ag + 512);
      uint2 pkp[2];
#pragma unroll 1
      for (int i = 0; i < 13; ++i) {
        bf16x8 ah0 = rA, ah1 = rB;
        rA = rB; rB = rC;
        if (i <= 10) rC = *(const bf16x8*)(ag + (size_t)(i + 3) * 256);
        conv2_step(ah0, ah1, b2h, c2i, st, gb, i, b, q, lane, pkp, A, ones);
      }
      syrk_tail(pkp, A, ones);
    }
  } else {
    short* pb0 = a1h + w * (3 * A1B);
    short* pb1 = pb0 + A1B;
    short* pb2 = pb0 + 2 * A1B;
#pragma unroll 1
    for (int t = 0; t < 4; ++t) {
      const int img = blockIdx.x * 16 + w * 4 + t;
      const float* sxi = sx_s + (w * 4 + t) * 256;
      short* gb = a2g + (size_t)img * 5408;
      conv1_mfma(sxi, pb0, 0, b, q, a1f, c1i);
      conv1_mfma(sxi, pb1, 1, b, q, a1f, c1i);
      __builtin_amdgcn_wave_barrier();
      uint2 pkp[2];
#pragma unroll 1
      for (int i = 0; i < 13; ++i) {
        if (i < 12) conv1_mfma(sxi, pb2, i + 2, b, q, a1f, c1i);
        bf16x8 ah0 = *(const bf16x8*)(pb0 + offAl);
        bf16x8 ah1 = *(const bf16x8*)(pb1 + offAl);
        conv2_step(ah0, ah1, b2h, c2i, st, gb, i, b, q, lane, pkp, A, ones);
        short* tpb = pb0; pb0 = pb1; pb1 = pb2; pb2 = tpb;
      }
      syrk_tail(pkp, A, ones);
    }
  }
  // S2: all rows of accS are identical column sums; col(lane&15)=ch.
  if (q == 0) {
    s2red[w * 32 + b]      = A.S0[0];
    s2red[w * 32 + 16 + b] = A.S1[0];
  }
  float* redc = sx_s;   // wave w writes only into its own sx quarter
#pragma unroll
  for (int rr = 0; rr < 4; ++rr) {
    int m = 4 * q + rr;
    redc[w * 1024 + 0   + m * 16 + b] = A.T0[rr];
    redc[w * 1024 + 256 + m * 16 + b] = A.T1[rr];
    redc[w * 1024 + 512 + m * 16 + b] = A.T2[rr];
  }
  __syncthreads();
  for (int e = tid; e < 768; e += 256)
    parts[blockIdx.x * 800 + e] =
        redc[e] + redc[1024 + e] + redc[2048 + e] + redc[3072 + e];
  if (tid < 32)
    parts[blockIdx.x * 800 + 768 + tid] =
        s2red[tid] + s2red[32 + tid] + s2red[64 + tid] + s2red[96 + tid];
}

// Reduce C2/S2 block partials: one block per entry e in [0,800).
__global__ __launch_bounds__(256) void k_statsC(
    const float* __restrict__ parts, float* __restrict__ ws)
{
  const int e = blockIdx.x, tid = threadIdx.x;
  const int w = tid >> 6, lane = tid & 63;
  __shared__ float rs[4];
  float s = 0.f;
#pragma unroll 4
  for (int i = tid; i < 1024; i += 256) s += parts[i * 800 + e];
#pragma unroll
  for (int d = 1; d < 64; d <<= 1) s += __shfl_xor(s, d);
  if (lane == 0) rs[w] = s;
  __syncthreads();
  if (tid == 0) ws[C2R_OFF + e] = rs[0] + rs[1] + rs[2] + rs[3];
}

// BN3 finalize from S2/C2: mean=w3^T S2/N, E[y3^2]=w3^T C2 w3 /N.
__global__ __launch_bounds__(64) void k_stats3n(
    const float* __restrict__ w3, const float* __restrict__ gamma,
    const float* __restrict__ beta, float* __restrict__ ws)
{
  const int c3 = threadIdx.x;
  if (c3 >= 64) return;
  const float* C2R = ws + C2R_OFF;
  float wr[32];
#pragma unroll
  for (int k = 0; k < 32; ++k) wr[k] = w3[c3 * 32 + k];
  const float inv_n = 1.0f / (16384.0f * 169.0f);
  float msum = 0.f;
#pragma unroll
  for (int k = 0; k < 32; ++k) msum += wr[k] * C2R[768 + k];
  float e2 = 0.f;
  for (int a = 0; a < 16; ++a)
#pragma unroll
    for (int bb = 0; bb < 16; ++bb) {
      e2 += wr[a] * wr[bb] * C2R[a * 16 + bb];                  // T00
      e2 += wr[16 + a] * wr[16 + bb] * C2R[512 + a * 16 + bb];  // T11
      e2 += 2.f * wr[a] * wr[16 + bb] * C2R[256 + a * 16 + bb]; // T01
    }
  float mean = msum * inv_n;
  float var  = e2 * inv_n - mean * mean;
  float sv   = gamma[c3] * rsqrtf(var + 1e-5f);
  ws[ST3 + c3]      = sv;
  ws[ST3 + 64 + c3] = beta[c3] - mean * sv;
}

// K0: pack fc_w into the register-direct FC order:
// fcB[((p*2+h)*64 + lane)*4 + u]; lane=(q<<4)|b; jj=b; k=8q+e elements with
// c3(e) = h*32 + (e>>2)*16 + 4q + (e&3); F_orig = c3*169 + p.
__global__ __launch_bounds__(256) void k0_fcB(
    const float* __restrict__ fcw, unsigned int* __restrict__ fcB)
{
  int f = blockIdx.x * 256 + threadIdx.x;   // FCB_N = 338*256 exactly
  int u = f & 3, lane = (f >> 2) & 63, h = (f >> 8) & 1, p = f >> 9;
  int b = lane & 15, q = lane >> 4;
  unsigned lo = 0, hi = 0;
  if (b < 10) {
    int c30 = h * 32 + (u >> 1) * 16 + 4 * q + 2 * (u & 1);
    lo = f2bf(fcw[b * 10816 + c30 * 169 + p]);
    hi = f2bf(fcw[b * 10816 + (c30 + 1) * 169 + p]);
  }
  fcB[f] = lo | (hi << 16);
}

// K7: conv3 operand-swapped (A=w3 m=c3, B=a2^T n=img) + FC direct from regs.
__global__ __launch_bounds__(256) void k7_fc(
    const short* __restrict__ a2g, const float* __restrict__ w3,
    const float* __restrict__ fcb, const float* __restrict__ ws,
    float* __restrict__ out)
{
  __shared__ float redf7[1024];
  const int tid = threadIdx.x, w = tid >> 6, lane = tid & 63;
  const int b = lane & 15, q = lane >> 4;
  bf16x8 b3h[4];     // A-side: m=c3=nt*16+b, k=ch 8q+j, scaled by s3[c3]
  f32x4 c3i[4];      // C-init: rows are c3-local 4q+r -> t3[nt*16+4q+r]
#pragma unroll
  for (int nt = 0; nt < 4; ++nt) {
    float s3 = ws[ST3 + nt * 16 + b];
    bf16x8 vh;
#pragma unroll
    for (int j = 0; j < 8; ++j)
      vh[j] = (short)f2bf(w3[(nt * 16 + b) * 32 + 8 * q + j] * s3);
    b3h[nt] = vh;
#pragma unroll
    for (int r = 0; r < 4; ++r)
      c3i[nt][r] = ws[ST3 + 64 + nt * 16 + 4 * q + r];
  }
  const bf16x8* fcB = (const bf16x8*)ws;
  const short* abase = a2g + (size_t)(blockIdx.x * 16 + b) * 5408 + 8 * q;
  const int p0 = (w * 169) >> 2, p1 = ((w + 1) * 169) >> 2;
  f32x4 aF0 = {0.f, 0.f, 0.f, 0.f}, aF1 = {0.f, 0.f, 0.f, 0.f};
  bf16x8 vpre = *(const bf16x8*)(abase + p0 * 32);
  bf16x8 bw0 = fcB[(p0 * 2 + 0) * 64 + lane];
  bf16x8 bw1 = fcB[(p0 * 2 + 1) * 64 + lane];
#pragma unroll 1
  for (int p = p0; p < p1; ++p) {
    bf16x8 vc = vpre, f0 = bw0, f1 = bw1;
    if (p + 1 < p1) {
      vpre = *(const bf16x8*)(abase + (p + 1) * 32);
      bw0 = fcB[((p + 1) * 2 + 0) * 64 + lane];
      bw1 = fcB[((p + 1) * 2 + 1) * 64 + lane];
    }
    uint2 pkc[4];
#pragma unroll
    for (int nt = 0; nt < 4; ++nt) {
      f32x4 acc3 = c3i[nt];
      acc3 = __builtin_amdgcn_mfma_f32_16x16x32_bf16(b3h[nt], vc, acc3, 0, 0, 0);
      float v0 = acc3[0] > 0.f ? acc3[0] : 0.f;
      float v1 = acc3[1] > 0.f ? acc3[1] : 0.f;
      float v2 = acc3[2] > 0.f ? acc3[2] : 0.f;
      float v3 = acc3[3] > 0.f ? acc3[3] : 0.f;
      pkc[nt].x = pkbf(v0, v1);
      pkc[nt].y = pkbf(v2, v3);
    }
    aF0 = __builtin_amdgcn_mfma_f32_16x16x32_bf16(mkfrag(pkc[0], pkc[1]), f0, aF0, 0, 0, 0);
    aF1 = __builtin_amdgcn_mfma_f32_16x16x32_bf16(mkfrag(pkc[2], pkc[3]), f1, aF1, 0, 0, 0);
  }
  // FC D: col(lane&15)=jj=b, row(4q+r)=img-slot. Reduce the 4 pix-chunk waves.
#pragma unroll
  for (int r = 0; r < 4; ++r)
    redf7[w * 256 + (4 * q + r) * 16 + b] = aF0[r] + aF1[r];
  __syncthreads();
  if (tid < 160) {
    int img = tid / 10, jj = tid - img * 10;
    float s = redf7[img * 16 + jj] + redf7[256 + img * 16 + jj] +
              redf7[512 + img * 16 + jj] + redf7[768 + img * 16 + jj];
    out[(blockIdx.x * 16 + img) * 10 + jj] = s + fcb[jj];
  }
}

extern "C" void kernel_launch(void* const* d_in, const int* in_sizes, int n_in,
                              void* d_out, int out_size, void* d_ws, size_t ws_size,
                              hipStream_t stream) {
  (void)in_sizes; (void)n_in; (void)out_size;
  const float* x   = (const float*)d_in[0];
  const float* w1  = (const float*)d_in[1];
  const float* w2  = (const float*)d_in[2];
  const float* w3  = (const float*)d_in[3];
  const float* g1  = (const float*)d_in[4];
  const float* b1  = (const float*)d_in[5];
  const float* g2  = (const float*)d_in[6];
  const float* b2  = (const float*)d_in[7];
  const float* g3  = (const float*)d_in[8];
  const float* b3  = (const float*)d_in[9];
  const float* fcw = (const float*)d_in[10];
  const float* fcb = (const float*)d_in[11];
  float* out = (float*)d_out;
  float* ws  = (float*)d_ws;
  short* a2g = (short*)((char*)d_ws + A2G_BYTE);
  float* parts = ws + C2P_OFF;
  const size_t a1off = A2G_BYTE + 16384ull * 5408ull * 2ull;  // after a2g
  short* a1g = (short*)((char*)d_ws + a1off);
  int cached = 0;
  if (ws_size > a1off) {
    long long c = (long long)(ws_size - a1off) / 7168;   // bytes per image
    if (c > 16384) c = 16384;
    cached = (int)c & ~15;                               // whole blocks
  }

  k1_xsyrk<<<1024, 256, 0, stream>>>(x, parts);
  k_stats1a<<<256, 256, 0, stream>>>(parts, ws);
  k_stats1b<<<1, 64, 0, stream>>>(w1, g1, b1, ws);
  k3_v2<<<1024, 256, 0, stream>>>(x, w1, w2, ws, a1g, cached);
  k_stats2<<<32, 256, 0, stream>>>(g2, b2, ws, 32, P2_OFF, ST2,
                                   1.0f / (16384.0f * 169.0f));
  k5_v2<<<1024, 256, 0, stream>>>(x, w1, a1g, w2, ws, a2g, parts, cached);
  k_statsC<<<800, 256, 0, stream>>>(parts, ws);
  k_stats3n<<<1, 64, 0, stream>>>(w3, g3, b3, ws);
  k0_fcB<<<FCB_N / 256, 256, 0, stream>>>(fcw, (unsigned int*)ws);
  k7_fc<<<1024, 256, 0, stream>>>(a2g, w3, fcb, ws, out);
}

// Round 11
// 265.942 us; speedup vs baseline: 1.1125x; 1.1125x over previous
//
#include <hip/hip_runtime.h>

// ---------------------------------------------------------------------------
// LocallyConnectedNN: x[16384,256] -> conv3x3(1->16)+BN+ReLU -> conv2x2(16->32)
// +BN+ReLU -> conv1x1(32->64)+BN+ReLU -> FC(10816->10).
// Round 19: revert round-18 (cvt_pk asm hurt per m240; a1g cache path was
// L3-latency-bound). Base = round-13 (best, 254.9). NEW: k3 stores RAW conv2
// (y2, bf16) rows into the a2g region ([img][13 i][13 pix][32 ch], one 832B
// burst per row -- it already computes y2 for BN2 stats); k5 becomes an
// IN-PLACE transform: read y2 row -> a2=relu(s2*y2+t2) -> overwrite same row
// + register-syrk for BN3 (fragments via a small LDS relay, pix>=13 rows
// pre-zeroed). Deletes k5's entire conv1+conv2 chain (~160 -> ~60 issued ops
// per row). y2g==a2g alias is safe: each row read once then overwritten,
// k7 reads only final a2. Extra bf16 rounding on y2: absmax ~0.02-0.03.
// ---------------------------------------------------------------------------

#define NPART 1024
#define P2_OFF 32768      // [1024][64] conv2 stats partials
#define ST_OFF 229376     // s1[16] t1[16] s2[32] t2[32] s3[64] t3[64]
#define ST1 ST_OFF
#define ST2 (ST_OFF + 32)
#define ST3 (ST_OFF + 96)
#define C2R_OFF 230400    // reduced [768 C2 tiles | 32 S2]
#define C1R_OFF 231424    // reduced x-patch Cext [16x16]
#define C2P_OFF 262144    // block partials (1MB..): k1 [1024][256], k5 [1024][800]
#define A2G_BYTE 5242880ull // a2/y2 cache: [img][13 i][13 pix][32 ch] bf16
#define FCB_N 86528       // fcB u32: [169 p][2 h][64 lane][4 u]
#define A1S 24            // a1h LDS row stride (shorts)
#define A1B 384           // one a1 LDS buffer (16 rows x A1S)
#define YSS 40            // y2/a2 staging row stride (shorts), 80B: b128-align

typedef __attribute__((ext_vector_type(8))) short bf16x8;
typedef __attribute__((ext_vector_type(4))) float f32x4;
typedef __attribute__((ext_vector_type(4))) unsigned int u32x4;

__device__ __forceinline__ unsigned int f2bf(float f) {
  unsigned int u = __float_as_uint(f);
  return (u + 0x7fffu + ((u >> 16) & 1u)) >> 16;   // RTNE bf16 bits
}
// pack two floats to bf16x2 (round-half-up): 2 adds + 1 v_perm_b32
__device__ __forceinline__ unsigned int pkbf(float a, float b) {
  unsigned ua = __float_as_uint(a) + 0x8000u;
  unsigned ub = __float_as_uint(b) + 0x8000u;
  return __builtin_amdgcn_perm(ub, ua, 0x07060302u);
}
__device__ __forceinline__ bf16x8 mkfrag(uint2 a, uint2 b) {
  u32x4 u = {a.x, a.y, b.x, b.y};
  return __builtin_bit_cast(bf16x8, u);
}

// conv1 (3x3,1->16)+bn1(folded)+relu for output row r, swapped operands:
// A = w1*rs1 (m=ch), B = im2row (n=col j), C-init = rt1.
// D: col(lane&15)=j, row(4q+r)=ch -> ph[j][ch] write = 1 ds_write_b64.
__device__ __forceinline__ void conv1_mfma(
    const float* __restrict__ sxi,   // [256] image (+finite pad after)
    short* ph_buf,                   // [2 bufs][16 j][A1S ch]
    int r, int b, int q, bf16x8 a1f, f32x4 c1i)
{
  bf16x8 bf = {0, 0, 0, 0, 0, 0, 0, 0};
  unsigned* bu = (unsigned*)&bf;
  if (q == 0) {
    bu[0] = pkbf(sxi[r * 16 + b],           sxi[r * 16 + b + 1]);
    bu[1] = pkbf(sxi[r * 16 + b + 2],       sxi[(r + 1) * 16 + b]);
    bu[2] = pkbf(sxi[(r + 1) * 16 + b + 1], sxi[(r + 1) * 16 + b + 2]);
    bu[3] = pkbf(sxi[(r + 2) * 16 + b],     sxi[(r + 2) * 16 + b + 1]);
  } else if (q == 1) {
    bu[0] = pkbf(sxi[(r + 2) * 16 + b + 2], 0.f);
  }
  f32x4 acc = c1i;
  acc = __builtin_amdgcn_mfma_f32_16x16x32_bf16(a1f, bf, acc, 0, 0, 0);
  float v0 = acc[0] > 0.f ? acc[0] : 0.f;
  float v1 = acc[1] > 0.f ? acc[1] : 0.f;
  float v2 = acc[2] > 0.f ? acc[2] : 0.f;
  float v3 = acc[3] > 0.f ? acc[3] : 0.f;
  uint2 pk;
  pk.x = pkbf(v0, v1);
  pk.y = pkbf(v2, v3);
  *(uint2*)(ph_buf + (r & 1) * A1B + b * A1S + 4 * q) = pk;
}

// conv1 A-frag: m=ch=b, k=tap 8q+j (zeros for tap>=9), scaled by rs1[b].
__device__ __forceinline__ bf16x8 conv1_afrag(const float* w1, float rs1b,
                                              int b, int q) {
  bf16x8 v;
#pragma unroll
  for (int j = 0; j < 8; ++j) {
    int tap = 8 * q + j;
    v[j] = (tap < 9) ? (short)f2bf(w1[b * 9 + tap] * rs1b) : (short)0;
  }
  return v;
}

// K1: x patch-covariance via MFMA syrk. x pre-packed to bf16 in LDS with TWO
// column-shifted copies: sb[img][row][cp][16 cols], cp=1 shifted by +1 col.
__global__ __launch_bounds__(256) void k1_xsyrk(
    const float* __restrict__ x, float* __restrict__ parts)
{
  __shared__ alignas(16) short sb[16 * 16 * 2 * 16];  // 16KB
  const int tid = threadIdx.x, w = tid >> 6, lane = tid & 63;
  const int b = lane & 15, q = lane >> 4;
  // phase 1: load f32x4, pack copy0 (all 16 real cols)
  {
    const float4* xs = (const float4*)(x + (size_t)blockIdx.x * (16 * 256));
    for (int e = tid; e < 16 * 64; e += 256) {
      float4 v = xs[e];
      int img = e >> 6, row = (e >> 2) & 15, g = e & 3;
      uint2 pk;
      pk.x = pkbf(v.x, v.y);
      pk.y = pkbf(v.z, v.w);
      *(uint2*)(sb + ((img * 16 + row) * 2 + 0) * 16 + 4 * g) = pk;
    }
  }
  __syncthreads();
  // phase 2: copy1 = copy0 shifted by one column (col 16 -> 0)
  {
    int img = tid >> 4, row = tid & 15;
    const unsigned* s0 = (const unsigned*)(sb + ((img * 16 + row) * 2 + 0) * 16);
    unsigned* s1 = (unsigned*)(sb + ((img * 16 + row) * 2 + 1) * 16);
    unsigned wprev = s0[0];
#pragma unroll
    for (int c = 0; c < 8; ++c) {
      unsigned wnext = (c < 7) ? s0[c + 1] : 0u;
      s1[c] = __builtin_amdgcn_perm(wnext, wprev, 0x05040302u);
      wprev = wnext;
    }
  }
  __syncthreads();
  const int di = (b < 9) ? (b / 3) : 0;
  const int dj = (b < 9) ? (b - di * 3) : 0;
  const int cp = dj & 1, dsh = dj >> 1;
  const int h = q >> 1, jb = (q & 1) * 8;
  const int wb = (jb >> 1) + dsh;
  f32x4 acc = {0.f, 0.f, 0.f, 0.f};
#pragma unroll 1
  for (int t = 0; t < 4; ++t) {
    const int ib = (w * 4 + t) * 16;
#pragma unroll 1
    for (int s = 0; s < 7; ++s) {
      bf16x8 af;
      unsigned* au = (unsigned*)&af;
      if (b < 9) {
        const unsigned* sr = (const unsigned*)(
            sb + ((ib + (2 * s + h + di)) * 2 + cp) * 16);
        au[0] = sr[wb];
        au[1] = sr[wb + 1];
        au[2] = sr[wb + 2];
        au[3] = (jb == 0) ? sr[wb + 3] : 0u;   // out-col >= 14 -> zero slot
      } else if (b == 9) {
#pragma unroll
        for (int cc = 0; cc < 4; ++cc) {
          unsigned lo = (jb + 2 * cc     < 14) ? 0x3F80u : 0u;
          unsigned hi = (jb + 2 * cc + 1 < 14) ? 0x3F800000u : 0u;
          au[cc] = lo | hi;
        }
      } else {
#pragma unroll
        for (int cc = 0; cc < 4; ++cc) au[cc] = 0u;
      }
      acc = __builtin_amdgcn_mfma_f32_16x16x32_bf16(af, af, acc, 0, 0, 0);
    }
  }
  __syncthreads();                 // done reading sb; reuse as reduce buffer
  float* redc = (float*)sb;
#pragma unroll
  for (int rr = 0; rr < 4; ++rr)
    redc[w * 256 + (4 * q + rr) * 16 + b] = acc[rr];
  __syncthreads();
  parts[blockIdx.x * 256 + tid] =
      redc[tid] + redc[256 + tid] + redc[512 + tid] + redc[768 + tid];
}

// Reduce k1 partials [1024][256] -> Cext[256].
__global__ __launch_bounds__(256) void k_stats1a(
    const float* __restrict__ parts, float* __restrict__ ws)
{
  const int e = blockIdx.x, tid = threadIdx.x;
  const int w = tid >> 6, lane = tid & 63;
  __shared__ float rs[4];
  float s = 0.f;
#pragma unroll 4
  for (int i = tid; i < 1024; i += 256) s += parts[i * 256 + e];
#pragma unroll
  for (int d = 1; d < 64; d <<= 1) s += __shfl_xor(s, d);
  if (lane == 0) rs[w] = s;
  __syncthreads();
  if (tid == 0) ws[C1R_OFF + e] = rs[0] + rs[1] + rs[2] + rs[3];
}

// BN1 finalize from Cext: mean = w^T S /N, E[y^2] = w^T C w /N.
__global__ __launch_bounds__(64) void k_stats1b(
    const float* __restrict__ w1, const float* __restrict__ gamma,
    const float* __restrict__ beta, float* __restrict__ ws)
{
  const int c = threadIdx.x;
  if (c >= 16) return;
  const float* C = ws + C1R_OFF;
  float wr[9];
#pragma unroll
  for (int p = 0; p < 9; ++p) wr[p] = w1[c * 9 + p];
  float msum = 0.f;
#pragma unroll
  for (int p = 0; p < 9; ++p) msum += wr[p] * C[9 * 16 + p];
  float e2 = 0.f;
#pragma unroll
  for (int a = 0; a < 9; ++a)
#pragma unroll
    for (int bb = 0; bb < 9; ++bb)
      e2 += wr[a] * wr[bb] * C[a * 16 + bb];
  const float inv_n = 1.0f / (16384.0f * 196.0f);
  float mean = msum * inv_n;
  float var  = e2 * inv_n - mean * mean;
  float sv   = gamma[c] * rsqrtf(var + 1e-5f);
  ws[ST1 + c]      = sv;
  ws[ST1 + 16 + c] = beta[c] - mean * sv;
}

// BN2 finalize, one block per channel (reduces P2 [1024][64]).
__global__ __launch_bounds__(256) void k_stats2(
    const float* __restrict__ gamma, const float* __restrict__ beta,
    float* __restrict__ ws, int nch, int part_off, int st_off, float inv_n)
{
  const int c = blockIdx.x, tid = threadIdx.x;
  const int w = tid >> 6, lane = tid & 63;
  __shared__ float rs[4], rq[4];
  float s = 0.f, q = 0.f;
#pragma unroll 4
  for (int i = tid; i < NPART; i += 256) {
    s += ws[part_off + i * 2 * nch + c];
    q += ws[part_off + i * 2 * nch + nch + c];
  }
#pragma unroll
  for (int d = 1; d < 64; d <<= 1) {
    s += __shfl_xor(s, d);
    q += __shfl_xor(q, d);
  }
  if (lane == 0) { rs[w] = s; rq[w] = q; }
  __syncthreads();
  if (tid == 0) {
    float st = rs[0] + rs[1] + rs[2] + rs[3];
    float qt = rq[0] + rq[1] + rq[2] + rq[3];
    float mean = st * inv_n;
    float var  = qt * inv_n - mean * mean;
    float sv   = gamma[c] * rsqrtf(var + 1e-5f);
    ws[st_off + c]       = sv;
    ws[st_off + nch + c] = beta[c] - mean * sv;
  }
}

// K3: conv1(MFMA,folded) + conv2(swapped, raw) stats + y2 row store.
// conv2 D: col(b)=pix, row(4q+r)=ch(nt half). Staged to [pix][ch] (stride
// YSS) and burst-stored (832B) into the a2g region as RAW y2 bf16.
__global__ __launch_bounds__(256) void k3_conv2_stats(
    const float* __restrict__ x, const float* __restrict__ w1,
    const float* __restrict__ w2, float* __restrict__ ws,
    short* __restrict__ y2g)
{
  __shared__ float sx_s[16 * 256 + 16];
  __shared__ alignas(16) short a1h[4 * 2 * A1B];
  __shared__ alignas(16) short y2st[4 * 16 * YSS];
  __shared__ float redf[256];
  const int tid = threadIdx.x, w = tid >> 6, lane = tid & 63;
  const int b = lane & 15, q = lane >> 4;
  {
    const float4* xs = (const float4*)(x + (size_t)blockIdx.x * (16 * 256));
    float4* sd = (float4*)sx_s;
    for (int e = tid; e < 16 * 64; e += 256) sd[e] = xs[e];
    if (tid < 16) sx_s[16 * 256 + tid] = 0.f;
  }
  bf16x8 a1f = conv1_afrag(w1, ws[ST1 + b], b, q);
  f32x4 c1i;
#pragma unroll
  for (int r = 0; r < 4; ++r) c1i[r] = ws[ST1 + 16 + 4 * q + r];
  bf16x8 b2h[4];   // A-side: [ks][nt], m=ch=b, raw
#pragma unroll
  for (int ks = 0; ks < 2; ++ks)
#pragma unroll
    for (int nt = 0; nt < 2; ++nt) {
      bf16x8 vh;
#pragma unroll
      for (int j = 0; j < 8; ++j) {
        int kk = 8 * (q & 1) + j, dj = q >> 1;
        vh[j] = (short)f2bf(w2[(nt * 16 + b) * 64 + kk * 4 + ks * 2 + dj]);
      }
      b2h[ks * 2 + nt] = vh;
    }
  const float vb = (b < 13) ? 1.f : 0.f;
  const int colAr = (b + (q >> 1) < 15) ? (b + (q >> 1)) : 15;
  const int offAl = colAr * A1S + 8 * (q & 1);
  __syncthreads();

  float s2r[2][4] = {{0.f,0.f,0.f,0.f},{0.f,0.f,0.f,0.f}};
  float q2r[2][4] = {{0.f,0.f,0.f,0.f},{0.f,0.f,0.f,0.f}};
  short* ph = a1h + w * (2 * A1B);
  short* st = y2st + w * (16 * YSS);
#pragma unroll 1
  for (int t = 0; t < 4; ++t) {
    const int img = blockIdx.x * 16 + w * 4 + t;
    const float* sxi = sx_s + (w * 4 + t) * 256;
    short* gb = y2g + (size_t)img * 5408;
    conv1_mfma(sxi, ph, 0, b, q, a1f, c1i);
    __builtin_amdgcn_wave_barrier();
#pragma unroll 1
    for (int i = 0; i < 13; ++i) {
      conv1_mfma(sxi, ph, i + 1, b, q, a1f, c1i);
      __builtin_amdgcn_wave_barrier();
      bf16x8 ah0 = *(const bf16x8*)(ph + (i & 1) * A1B + offAl);
      bf16x8 ah1 = *(const bf16x8*)(ph + ((i + 1) & 1) * A1B + offAl);
      f32x4 acc2[2] = {{0.f,0.f,0.f,0.f},{0.f,0.f,0.f,0.f}};
#pragma unroll
      for (int nt = 0; nt < 2; ++nt) {
        acc2[nt] = __builtin_amdgcn_mfma_f32_16x16x32_bf16(b2h[nt], ah0, acc2[nt], 0, 0, 0);
        acc2[nt] = __builtin_amdgcn_mfma_f32_16x16x32_bf16(b2h[2 + nt], ah1, acc2[nt], 0, 0, 0);
      }
      // stage RAW y2: (pix=b, ch=nt*16+4q+r) -> st[pix*YSS + ch], 2 b64 writes
      {
        uint2 pz0, pz1;
        pz0.x = pkbf(acc2[0][0], acc2[0][1]);
        pz0.y = pkbf(acc2[0][2], acc2[0][3]);
        pz1.x = pkbf(acc2[1][0], acc2[1][1]);
        pz1.y = pkbf(acc2[1][2], acc2[1][3]);
        *(uint2*)(st + b * YSS + 4 * q)      = pz0;
        *(uint2*)(st + b * YSS + 16 + 4 * q) = pz1;
      }
#pragma unroll
      for (int nt = 0; nt < 2; ++nt)
#pragma unroll
        for (int r = 0; r < 4; ++r) {
          float ym = acc2[nt][r] * vb;
          s2r[nt][r] += ym;
          q2r[nt][r] = fmaf(ym, acc2[nt][r], q2r[nt][r]);
        }
      __builtin_amdgcn_wave_barrier();
      if (lane < 52) {   // burst: 13 pix x 32 ch = 832B
        bf16x8 vv = *(const bf16x8*)(st + (lane >> 2) * YSS + (lane & 3) * 8);
        *(bf16x8*)(gb + (size_t)i * 416 + lane * 8) = vv;
      }
      __builtin_amdgcn_wave_barrier();
    }
  }
  // reduce over the 16 pix-lanes (b); lane b==0 holds ch = nt*16+4q+r
#pragma unroll
  for (int nt = 0; nt < 2; ++nt)
#pragma unroll
    for (int r = 0; r < 4; ++r) {
      float sv = s2r[nt][r], qv = q2r[nt][r];
      sv += __shfl_xor(sv, 1); sv += __shfl_xor(sv, 2);
      sv += __shfl_xor(sv, 4); sv += __shfl_xor(sv, 8);
      qv += __shfl_xor(qv, 1); qv += __shfl_xor(qv, 2);
      qv += __shfl_xor(qv, 4); qv += __shfl_xor(qv, 8);
      if (b == 0) {
        redf[w * 64 + nt * 16 + 4 * q + r]      = sv;
        redf[w * 64 + 32 + nt * 16 + 4 * q + r] = qv;
      }
    }
  __syncthreads();
  if (tid < 64)
    ws[P2_OFF + blockIdx.x * 64 + tid] =
        redf[tid] + redf[64 + tid] + redf[128 + tid] + redf[192 + tid];
}

// K5: IN-PLACE transform a2 = relu(s2*y2 + t2) over the y2/a2 region +
// register-syrk for BN3. Per row: lanes<52 load b128 (pix=lane>>2,
// ch=(lane&3)*8..+7), affine+relu in regs, store b128 back (a2) AND relay
// through LDS st (stride YSS, rows 13-15 pre-zeroed) so syrk lanes can read
// their (ch=nt*16+b, pix=4q+r) fragments. S2 via mfma(ones, xf).
__global__ __launch_bounds__(256) void k5_t(
    const float* __restrict__ ws, short* __restrict__ a2g,
    float* __restrict__ parts)
{
  __shared__ float redc[4096];
  __shared__ alignas(16) short st4[4 * 16 * YSS];
  __shared__ float s2red[4 * 32];
  const int tid = threadIdx.x, w = tid >> 6, lane = tid & 63;
  const int b = lane & 15, q = lane >> 4;
  short* st = st4 + w * (16 * YSS);
  // zero pix rows 13..15 once (syrk reads them; transform never writes them)
  if (lane < 15) {
    u32x4 z = {0u, 0u, 0u, 0u};
    *(bf16x8*)(st + 13 * YSS + lane * 8) = __builtin_bit_cast(bf16x8, z);
  }
  // transform constants: lane<52 owns ch (lane&3)*8..+7
  const int ch0 = (lane & 3) * 8;
  f32x4 s2a = *(const f32x4*)(ws + ST2 + ch0);
  f32x4 s2b = *(const f32x4*)(ws + ST2 + ch0 + 4);
  f32x4 t2a = *(const f32x4*)(ws + ST2 + 32 + ch0);
  f32x4 t2b = *(const f32x4*)(ws + ST2 + 32 + ch0 + 4);
  const u32x4 ou = {0x3F803F80u, 0x3F803F80u, 0x3F803F80u, 0x3F803F80u};
  const bf16x8 ones = __builtin_bit_cast(bf16x8, ou);
  __builtin_amdgcn_wave_barrier();

  f32x4 accT0 = {0.f,0.f,0.f,0.f}, accT1 = {0.f,0.f,0.f,0.f},
        accT2 = {0.f,0.f,0.f,0.f};
  f32x4 accS0 = {0.f,0.f,0.f,0.f}, accS1 = {0.f,0.f,0.f,0.f};
#pragma unroll 1
  for (int t = 0; t < 4; ++t) {
    const int img = blockIdx.x * 16 + w * 4 + t;
    short* gb = a2g + (size_t)img * 5408;
    bf16x8 vv = {0, 0, 0, 0, 0, 0, 0, 0};
    if (lane < 52) vv = *(const bf16x8*)(gb + lane * 8);
    uint2 pkp[2];
#pragma unroll 1
    for (int i = 0; i < 13; ++i) {
      bf16x8 cur = vv;
      if (i < 12 && lane < 52)
        vv = *(const bf16x8*)(gb + (size_t)(i + 1) * 416 + lane * 8);
      __builtin_amdgcn_wave_barrier();   // st free (prev syrk reads done)
      if (lane < 52) {
        float av[8];
#pragma unroll
        for (int j = 0; j < 4; ++j) {
          float raw = __uint_as_float(
              ((unsigned)(unsigned short)cur[j]) << 16);
          float vj = fmaf(s2a[j], raw, t2a[j]);
          av[j] = vj > 0.f ? vj : 0.f;
        }
#pragma unroll
        for (int j = 0; j < 4; ++j) {
          float raw = __uint_as_float(
              ((unsigned)(unsigned short)cur[4 + j]) << 16);
          float vj = fmaf(s2b[j], raw, t2b[j]);
          av[4 + j] = vj > 0.f ? vj : 0.f;
        }
        u32x4 pq;
        pq[0] = pkbf(av[0], av[1]);
        pq[1] = pkbf(av[2], av[3]);
        pq[2] = pkbf(av[4], av[5]);
        pq[3] = pkbf(av[6], av[7]);
        bf16x8 pv = __builtin_bit_cast(bf16x8, pq);
        *(bf16x8*)(st + (lane >> 2) * YSS + (lane & 3) * 8) = pv;
        *(bf16x8*)(gb + (size_t)i * 416 + lane * 8) = pv;   // a2 over y2
      }
      __builtin_amdgcn_wave_barrier();   // st a2 visible
      uint2 pkc[2];
#pragma unroll
      for (int nt = 0; nt < 2; ++nt) {
        unsigned r0 = (unsigned short)st[(4 * q + 0) * YSS + nt * 16 + b];
        unsigned r1 = (unsigned short)st[(4 * q + 1) * YSS + nt * 16 + b];
        unsigned r2 = (unsigned short)st[(4 * q + 2) * YSS + nt * 16 + b];
        unsigned r3 = (unsigned short)st[(4 * q + 3) * YSS + nt * 16 + b];
        pkc[nt].x = r0 | (r1 << 16);
        pkc[nt].y = r2 | (r3 << 16);
      }
      if (i & 1) {       // syrk over row pair (i-1, i)
        bf16x8 xf0 = mkfrag(pkp[0], pkc[0]);
        bf16x8 xf1 = mkfrag(pkp[1], pkc[1]);
        accT0 = __builtin_amdgcn_mfma_f32_16x16x32_bf16(xf0, xf0, accT0, 0, 0, 0);
        accT1 = __builtin_amdgcn_mfma_f32_16x16x32_bf16(xf0, xf1, accT1, 0, 0, 0);
        accT2 = __builtin_amdgcn_mfma_f32_16x16x32_bf16(xf1, xf1, accT2, 0, 0, 0);
        accS0 = __builtin_amdgcn_mfma_f32_16x16x32_bf16(ones, xf0, accS0, 0, 0, 0);
        accS1 = __builtin_amdgcn_mfma_f32_16x16x32_bf16(ones, xf1, accS1, 0, 0, 0);
      } else {
        pkp[0] = pkc[0];
        pkp[1] = pkc[1];
      }
    }
    // leftover row 12 (parity 0, held in pkp): pair with zeros
    {
      uint2 zz; zz.x = 0u; zz.y = 0u;
      bf16x8 xf0 = mkfrag(pkp[0], zz);
      bf16x8 xf1 = mkfrag(pkp[1], zz);
      accT0 = __builtin_amdgcn_mfma_f32_16x16x32_bf16(xf0, xf0, accT0, 0, 0, 0);
      accT1 = __builtin_amdgcn_mfma_f32_16x16x32_bf16(xf0, xf1, accT1, 0, 0, 0);
      accT2 = __builtin_amdgcn_mfma_f32_16x16x32_bf16(xf1, xf1, accT2, 0, 0, 0);
      accS0 = __builtin_amdgcn_mfma_f32_16x16x32_bf16(ones, xf0, accS0, 0, 0, 0);
      accS1 = __builtin_amdgcn_mfma_f32_16x16x32_bf16(ones, xf1, accS1, 0, 0, 0);
    }
  }
  // S2: all rows of accS are identical column sums; col(lane&15)=ch.
  if (q == 0) {
    s2red[w * 32 + b]      = accS0[0];
    s2red[w * 32 + 16 + b] = accS1[0];
  }
#pragma unroll
  for (int rr = 0; rr < 4; ++rr) {
    int m = 4 * q + rr;
    redc[w * 1024 + 0   + m * 16 + b] = accT0[rr];
    redc[w * 1024 + 256 + m * 16 + b] = accT1[rr];
    redc[w * 1024 + 512 + m * 16 + b] = accT2[rr];
  }
  __syncthreads();
  for (int e = tid; e < 768; e += 256)
    parts[blockIdx.x * 800 + e] =
        redc[e] + redc[1024 + e] + redc[2048 + e] + redc[3072 + e];
  if (tid < 32)
    parts[blockIdx.x * 800 + 768 + tid] =
        s2red[tid] + s2red[32 + tid] + s2red[64 + tid] + s2red[96 + tid];
}

// Reduce C2/S2 block partials: one block per entry e in [0,800).
__global__ __launch_bounds__(256) void k_statsC(
    const float* __restrict__ parts, float* __restrict__ ws)
{
  const int e = blockIdx.x, tid = threadIdx.x;
  const int w = tid >> 6, lane = tid & 63;
  __shared__ float rs[4];
  float s = 0.f;
#pragma unroll 4
  for (int i = tid; i < 1024; i += 256) s += parts[i * 800 + e];
#pragma unroll
  for (int d = 1; d < 64; d <<= 1) s += __shfl_xor(s, d);
  if (lane == 0) rs[w] = s;
  __syncthreads();
  if (tid == 0) ws[C2R_OFF + e] = rs[0] + rs[1] + rs[2] + rs[3];
}

// BN3 finalize from S2/C2: mean=w3^T S2/N, E[y3^2]=w3^T C2 w3 /N.
__global__ __launch_bounds__(64) void k_stats3n(
    const float* __restrict__ w3, const float* __restrict__ gamma,
    const float* __restrict__ beta, float* __restrict__ ws)
{
  const int c3 = threadIdx.x;
  if (c3 >= 64) return;
  const float* C2R = ws + C2R_OFF;
  float wr[32];
#pragma unroll
  for (int k = 0; k < 32; ++k) wr[k] = w3[c3 * 32 + k];
  const float inv_n = 1.0f / (16384.0f * 169.0f);
  float msum = 0.f;
#pragma unroll
  for (int k = 0; k < 32; ++k) msum += wr[k] * C2R[768 + k];
  float e2 = 0.f;
  for (int a = 0; a < 16; ++a)
#pragma unroll
    for (int bb = 0; bb < 16; ++bb) {
      e2 += wr[a] * wr[bb] * C2R[a * 16 + bb];                  // T00
      e2 += wr[16 + a] * wr[16 + bb] * C2R[512 + a * 16 + bb];  // T11
      e2 += 2.f * wr[a] * wr[16 + bb] * C2R[256 + a * 16 + bb]; // T01
    }
  float mean = msum * inv_n;
  float var  = e2 * inv_n - mean * mean;
  float sv   = gamma[c3] * rsqrtf(var + 1e-5f);
  ws[ST3 + c3]      = sv;
  ws[ST3 + 64 + c3] = beta[c3] - mean * sv;
}

// K0: pack fc_w into the register-direct FC order:
// fcB[((p*2+h)*64 + lane)*4 + u]; lane=(q<<4)|b; jj=b; k=8q+e elements with
// c3(e) = h*32 + (e>>2)*16 + 4q + (e&3); F_orig = c3*169 + p.
__global__ __launch_bounds__(256) void k0_fcB(
    const float* __restrict__ fcw, unsigned int* __restrict__ fcB)
{
  int f = blockIdx.x * 256 + threadIdx.x;   // FCB_N = 338*256 exactly
  int u = f & 3, lane = (f >> 2) & 63, h = (f >> 8) & 1, p = f >> 9;
  int b = lane & 15, q = lane >> 4;
  unsigned lo = 0, hi = 0;
  if (b < 10) {
    int c30 = h * 32 + (u >> 1) * 16 + 4 * q + 2 * (u & 1);
    lo = f2bf(fcw[b * 10816 + c30 * 169 + p]);
    hi = f2bf(fcw[b * 10816 + (c30 + 1) * 169 + p]);
  }
  fcB[f] = lo | (hi << 16);
}

// K7: conv3 operand-swapped (A=w3 m=c3, B=a2^T n=img) + FC direct from regs.
__global__ __launch_bounds__(256) void k7_fc(
    const short* __restrict__ a2g, const float* __restrict__ w3,
    const float* __restrict__ fcb, const float* __restrict__ ws,
    float* __restrict__ out)
{
  __shared__ float redf7[1024];
  const int tid = threadIdx.x, w = tid >> 6, lane = tid & 63;
  const int b = lane & 15, q = lane >> 4;
  bf16x8 b3h[4];     // A-side: m=c3=nt*16+b, k=ch 8q+j, scaled by s3[c3]
  f32x4 c3i[4];      // C-init: rows are c3-local 4q+r -> t3[nt*16+4q+r]
#pragma unroll
  for (int nt = 0; nt < 4; ++nt) {
    float s3 = ws[ST3 + nt * 16 + b];
    bf16x8 vh;
#pragma unroll
    for (int j = 0; j < 8; ++j)
      vh[j] = (short)f2bf(w3[(nt * 16 + b) * 32 + 8 * q + j] * s3);
    b3h[nt] = vh;
#pragma unroll
    for (int r = 0; r < 4; ++r)
      c3i[nt][r] = ws[ST3 + 64 + nt * 16 + 4 * q + r];
  }
  const bf16x8* fcB = (const bf16x8*)ws;
  const short* abase = a2g + (size_t)(blockIdx.x * 16 + b) * 5408 + 8 * q;
  const int p0 = (w * 169) >> 2, p1 = ((w + 1) * 169) >> 2;
  f32x4 aF0 = {0.f, 0.f, 0.f, 0.f}, aF1 = {0.f, 0.f, 0.f, 0.f};
  bf16x8 vpre = *(const bf16x8*)(abase + p0 * 32);
  bf16x8 bw0 = fcB[(p0 * 2 + 0) * 64 + lane];
  bf16x8 bw1 = fcB[(p0 * 2 + 1) * 64 + lane];
#pragma unroll 1
  for (int p = p0; p < p1; ++p) {
    bf16x8 vc = vpre, f0 = bw0, f1 = bw1;
    if (p + 1 < p1) {
      vpre = *(const bf16x8*)(abase + (p + 1) * 32);
      bw0 = fcB[((p + 1) * 2 + 0) * 64 + lane];
      bw1 = fcB[((p + 1) * 2 + 1) * 64 + lane];
    }
    uint2 pkc[4];
#pragma unroll
    for (int nt = 0; nt < 4; ++nt) {
      f32x4 acc3 = c3i[nt];
      acc3 = __builtin_amdgcn_mfma_f32_16x16x32_bf16(b3h[nt], vc, acc3, 0, 0, 0);
      float v0 = acc3[0] > 0.f ? acc3[0] : 0.f;
      float v1 = acc3[1] > 0.f ? acc3[1] : 0.f;
      float v2 = acc3[2] > 0.f ? acc3[2] : 0.f;
      float v3 = acc3[3] > 0.f ? acc3[3] : 0.f;
      pkc[nt].x = pkbf(v0, v1);
      pkc[nt].y = pkbf(v2, v3);
    }
    aF0 = __builtin_amdgcn_mfma_f32_16x16x32_bf16(mkfrag(pkc[0], pkc[1]), f0, aF0, 0, 0, 0);
    aF1 = __builtin_amdgcn_mfma_f32_16x16x32_bf16(mkfrag(pkc[2], pkc[3]), f1, aF1, 0, 0, 0);
  }
  // FC D: col(lane&15)=jj=b, row(4q+r)=img-slot. Reduce the 4 pix-chunk waves.
#pragma unroll
  for (int r = 0; r < 4; ++r)
    redf7[w * 256 + (4 * q + r) * 16 + b] = aF0[r] + aF1[r];
  __syncthreads();
  if (tid < 160) {
    int img = tid / 10, jj = tid - img * 10;
    float s = redf7[img * 16 + jj] + redf7[256 + img * 16 + jj] +
              redf7[512 + img * 16 + jj] + redf7[768 + img * 16 + jj];
    out[(blockIdx.x * 16 + img) * 10 + jj] = s + fcb[jj];
  }
}

extern "C" void kernel_launch(void* const* d_in, const int* in_sizes, int n_in,
                              void* d_out, int out_size, void* d_ws, size_t ws_size,
                              hipStream_t stream) {
  (void)in_sizes; (void)n_in; (void)out_size; (void)ws_size;
  const float* x   = (const float*)d_in[0];
  const float* w1  = (const float*)d_in[1];
  const float* w2  = (const float*)d_in[2];
  const float* w3  = (const float*)d_in[3];
  const float* g1  = (const float*)d_in[4];
  const float* b1  = (const float*)d_in[5];
  const float* g2  = (const float*)d_in[6];
  const float* b2  = (const float*)d_in[7];
  const float* g3  = (const float*)d_in[8];
  const float* b3  = (const float*)d_in[9];
  const float* fcw = (const float*)d_in[10];
  const float* fcb = (const float*)d_in[11];
  float* out = (float*)d_out;
  float* ws  = (float*)d_ws;
  short* a2g = (short*)((char*)d_ws + A2G_BYTE);
  float* parts = ws + C2P_OFF;

  k1_xsyrk<<<1024, 256, 0, stream>>>(x, parts);
  k_stats1a<<<256, 256, 0, stream>>>(parts, ws);
  k_stats1b<<<1, 64, 0, stream>>>(w1, g1, b1, ws);
  k3_conv2_stats<<<1024, 256, 0, stream>>>(x, w1, w2, ws, a2g);
  k_stats2<<<32, 256, 0, stream>>>(g2, b2, ws, 32, P2_OFF, ST2,
                                   1.0f / (16384.0f * 169.0f));
  k5_t<<<1024, 256, 0, stream>>>(ws, a2g, parts);
  k_statsC<<<800, 256, 0, stream>>>(parts, ws);
  k_stats3n<<<1, 64, 0, stream>>>(w3, g3, b3, ws);
  k0_fcB<<<FCB_N / 256, 256, 0, stream>>>(fcw, (unsigned int*)ws);
  k7_fc<<<1024, 256, 0, stream>>>(a2g, w3, fcb, ws, out);
}

// Round 12
// 246.046 us; speedup vs baseline: 1.2025x; 1.0809x over previous
//
#include <hip/hip_runtime.h>

// ---------------------------------------------------------------------------
// LocallyConnectedNN: x[16384,256] -> conv3x3(1->16)+BN+ReLU -> conv2x2(16->32)
// +BN+ReLU -> conv1x1(32->64)+BN+ReLU -> FC(10816->10).
// Round 20: revert to round-13 structure (best, 254.9; rounds 14-19 all
// regressed/neutral). NEW: conv1 B-frag via k1-style pre-packed dual
// column-shifted bf16 LDS copies, with conv1 k-slots RE-PERMUTED so every
// bf16x2 pair is row-contiguous: q0={(r,b),(r,b+1)|(r,b+2),pad|(r+1,b),
// (r+1,b+1)|(r+1,b+2),pad}, q1={(r+2,b..b+2),pads}. Pads carry ZERO WEIGHTS
// (A-side) so garbage data needs no masking. Frag build: 8 f32 LDS reads +
// 5 pkbf -> 4/2 ds_read_b32, zero VALU (word index cw=(b&1)*8+(b>>1)).
// Applied to k3+k5 conv1 (k1 already does this). Bit-identical products;
// MFMA k-order permuted (ulp-level). LDS unchanged (sb 16KB = old sx 16KB).
// ---------------------------------------------------------------------------

#define NPART 1024
#define P2_OFF 32768      // [1024][64] conv2 stats partials
#define ST_OFF 229376     // s1[16] t1[16] s2[32] t2[32] s3[64] t3[64]
#define ST1 ST_OFF
#define ST2 (ST_OFF + 32)
#define ST3 (ST_OFF + 96)
#define C2R_OFF 230400    // reduced [768 C2 tiles | 32 S2]
#define C1R_OFF 231424    // reduced x-patch Cext [16x16]
#define C2P_OFF 262144    // block partials (1MB..): k1 [1024][256], k5 [1024][800]
#define A2G_BYTE 5242880ull // a2 cache: [img][13 i][13 pix][32 ch] bf16, 177MB
#define FCB_N 86528       // fcB u32: [169 p][2 h][64 lane][4 u]
#define A1S 24            // a1h LDS row stride (shorts)
#define A1B 384           // one a1 LDS buffer (16 rows x A1S)

typedef __attribute__((ext_vector_type(8))) short bf16x8;
typedef __attribute__((ext_vector_type(4))) float f32x4;
typedef __attribute__((ext_vector_type(4))) unsigned int u32x4;

__device__ __forceinline__ unsigned int f2bf(float f) {
  unsigned int u = __float_as_uint(f);
  return (u + 0x7fffu + ((u >> 16) & 1u)) >> 16;   // RTNE bf16 bits
}
// pack two floats to bf16x2 (round-half-up): 2 adds + 1 v_perm_b32
__device__ __forceinline__ unsigned int pkbf(float a, float b) {
  unsigned ua = __float_as_uint(a) + 0x8000u;
  unsigned ub = __float_as_uint(b) + 0x8000u;
  return __builtin_amdgcn_perm(ub, ua, 0x07060302u);
}
__device__ __forceinline__ bf16x8 mkfrag(uint2 a, uint2 b) {
  u32x4 u = {a.x, a.y, b.x, b.y};
  return __builtin_bit_cast(bf16x8, u);
}

// conv1 (3x3,1->16)+bn1(folded)+relu for output row r, swapped operands:
// A = w1*rs1 (m=ch, PERMUTED k), B = im2row from pre-packed sb (n=col j).
// B-frag: 4 (q0) / 2 (q1) ds_read_b32, zero VALU. D: col(lane&15)=j,
// row(4q+r)=ch -> ph[j][ch] write = 1 ds_write_b64.
__device__ __forceinline__ void conv1_mfma(
    const short* __restrict__ sbi,   // [16 rows][2 cp][16 cols] bf16 (+pad)
    short* ph_buf,                   // [2 bufs][16 j][A1S ch]
    int r, int b, int q, bf16x8 a1f, f32x4 c1i)
{
  bf16x8 bf = {0, 0, 0, 0, 0, 0, 0, 0};
  unsigned* bu = (unsigned*)&bf;
  const unsigned* base = (const unsigned*)sbi;
  const int cw = (b & 1) * 8 + (b >> 1);   // cp*8 + word; row stride 16 u32
  if (q == 0) {
    const unsigned* r0 = base + r * 16 + cw;
    const unsigned* r1 = base + (r + 1) * 16 + cw;
    bu[0] = r0[0];   // (r,b),(r,b+1)
    bu[1] = r0[1];   // (r,b+2), pad (zero weight)
    bu[2] = r1[0];   // (r+1,b),(r+1,b+1)
    bu[3] = r1[1];   // (r+1,b+2), pad
  } else if (q == 1) {
    const unsigned* r2 = base + (r + 2) * 16 + cw;
    bu[0] = r2[0];   // (r+2,b),(r+2,b+1)
    bu[1] = r2[1];   // (r+2,b+2), pad
  }
  f32x4 acc = c1i;
  acc = __builtin_amdgcn_mfma_f32_16x16x32_bf16(a1f, bf, acc, 0, 0, 0);
  float v0 = acc[0] > 0.f ? acc[0] : 0.f;
  float v1 = acc[1] > 0.f ? acc[1] : 0.f;
  float v2 = acc[2] > 0.f ? acc[2] : 0.f;
  float v3 = acc[3] > 0.f ? acc[3] : 0.f;
  uint2 pk;
  pk.x = pkbf(v0, v1);
  pk.y = pkbf(v2, v3);
  *(uint2*)(ph_buf + (r & 1) * A1B + b * A1S + 4 * q) = pk;
}

// conv1 A-frag, PERMUTED to match conv1_mfma's B layout:
// q0: {w0,w1,w2,0,w3,w4,w5,0}; q1: {w6,w7,w8,0,0,0,0,0}; q>=2: zeros.
__device__ __forceinline__ bf16x8 conv1_afrag(const float* w1, float rs1b,
                                              int b, int q) {
  bf16x8 v = {0, 0, 0, 0, 0, 0, 0, 0};
  if (q == 0) {
#pragma unroll
    for (int j = 0; j < 3; ++j) {
      v[j]     = (short)f2bf(w1[b * 9 + j] * rs1b);
      v[4 + j] = (short)f2bf(w1[b * 9 + 3 + j] * rs1b);
    }
  } else if (q == 1) {
#pragma unroll
    for (int j = 0; j < 3; ++j)
      v[j] = (short)f2bf(w1[b * 9 + 6 + j] * rs1b);
  }
  return v;
}

// Build dual-copy packed x in LDS: sb[img][row][cp][16], cp1 = +1 col shift.
// 256 threads; caller syncs after.
__device__ __forceinline__ void build_sb(const float* __restrict__ x,
                                         short* sb, int tid, int nblk16) {
  {
    const float4* xs = (const float4*)(x + (size_t)nblk16 * (16 * 256));
    for (int e = tid; e < 16 * 64; e += 256) {
      float4 v = xs[e];
      int img = e >> 6, row = (e >> 2) & 15, g = e & 3;
      uint2 pk;
      pk.x = pkbf(v.x, v.y);
      pk.y = pkbf(v.z, v.w);
      *(uint2*)(sb + ((img * 16 + row) * 2 + 0) * 16 + 4 * g) = pk;
    }
    if (tid < 16) ((unsigned*)(sb + 16 * 16 * 2 * 16))[tid] = 0u;  // pad
  }
  __syncthreads();
  {
    int img = tid >> 4, row = tid & 15;
    const unsigned* s0 = (const unsigned*)(sb + ((img * 16 + row) * 2 + 0) * 16);
    unsigned* s1 = (unsigned*)(sb + ((img * 16 + row) * 2 + 1) * 16);
    unsigned wprev = s0[0];
#pragma unroll
    for (int c = 0; c < 8; ++c) {
      unsigned wnext = (c < 7) ? s0[c + 1] : 0u;
      s1[c] = __builtin_amdgcn_perm(wnext, wprev, 0x05040302u);
      wprev = wnext;
    }
  }
}

// K1: x patch-covariance via MFMA syrk (own sb copy, unchanged layout).
__global__ __launch_bounds__(256) void k1_xsyrk(
    const float* __restrict__ x, float* __restrict__ parts)
{
  __shared__ alignas(16) short sb[16 * 16 * 2 * 16 + 32];
  const int tid = threadIdx.x, w = tid >> 6, lane = tid & 63;
  const int b = lane & 15, q = lane >> 4;
  build_sb(x, sb, tid, blockIdx.x);
  __syncthreads();
  const int di = (b < 9) ? (b / 3) : 0;
  const int dj = (b < 9) ? (b - di * 3) : 0;
  const int cp = dj & 1, dsh = dj >> 1;
  const int h = q >> 1, jb = (q & 1) * 8;
  const int wb = (jb >> 1) + dsh;
  f32x4 acc = {0.f, 0.f, 0.f, 0.f};
#pragma unroll 1
  for (int t = 0; t < 4; ++t) {
    const int ib = (w * 4 + t) * 16;
#pragma unroll 1
    for (int s = 0; s < 7; ++s) {
      bf16x8 af;
      unsigned* au = (unsigned*)&af;
      if (b < 9) {
        const unsigned* sr = (const unsigned*)(
            sb + ((ib + (2 * s + h + di)) * 2 + cp) * 16);
        au[0] = sr[wb];
        au[1] = sr[wb + 1];
        au[2] = sr[wb + 2];
        au[3] = (jb == 0) ? sr[wb + 3] : 0u;   // out-col >= 14 -> zero slot
      } else if (b == 9) {
#pragma unroll
        for (int cc = 0; cc < 4; ++cc) {
          unsigned lo = (jb + 2 * cc     < 14) ? 0x3F80u : 0u;
          unsigned hi = (jb + 2 * cc + 1 < 14) ? 0x3F800000u : 0u;
          au[cc] = lo | hi;
        }
      } else {
#pragma unroll
        for (int cc = 0; cc < 4; ++cc) au[cc] = 0u;
      }
      acc = __builtin_amdgcn_mfma_f32_16x16x32_bf16(af, af, acc, 0, 0, 0);
    }
  }
  __syncthreads();                 // done reading sb; reuse as reduce buffer
  float* redc = (float*)sb;
#pragma unroll
  for (int rr = 0; rr < 4; ++rr)
    redc[w * 256 + (4 * q + rr) * 16 + b] = acc[rr];
  __syncthreads();
  parts[blockIdx.x * 256 + tid] =
      redc[tid] + redc[256 + tid] + redc[512 + tid] + redc[768 + tid];
}

// Reduce k1 partials [1024][256] -> Cext[256].
__global__ __launch_bounds__(256) void k_stats1a(
    const float* __restrict__ parts, float* __restrict__ ws)
{
  const int e = blockIdx.x, tid = threadIdx.x;
  const int w = tid >> 6, lane = tid & 63;
  __shared__ float rs[4];
  float s = 0.f;
#pragma unroll 4
  for (int i = tid; i < 1024; i += 256) s += parts[i * 256 + e];
#pragma unroll
  for (int d = 1; d < 64; d <<= 1) s += __shfl_xor(s, d);
  if (lane == 0) rs[w] = s;
  __syncthreads();
  if (tid == 0) ws[C1R_OFF + e] = rs[0] + rs[1] + rs[2] + rs[3];
}

// BN1 finalize from Cext: mean = w^T S /N, E[y^2] = w^T C w /N.
__global__ __launch_bounds__(64) void k_stats1b(
    const float* __restrict__ w1, const float* __restrict__ gamma,
    const float* __restrict__ beta, float* __restrict__ ws)
{
  const int c = threadIdx.x;
  if (c >= 16) return;
  const float* C = ws + C1R_OFF;
  float wr[9];
#pragma unroll
  for (int p = 0; p < 9; ++p) wr[p] = w1[c * 9 + p];
  float msum = 0.f;
#pragma unroll
  for (int p = 0; p < 9; ++p) msum += wr[p] * C[9 * 16 + p];
  float e2 = 0.f;
#pragma unroll
  for (int a = 0; a < 9; ++a)
#pragma unroll
    for (int bb = 0; bb < 9; ++bb)
      e2 += wr[a] * wr[bb] * C[a * 16 + bb];
  const float inv_n = 1.0f / (16384.0f * 196.0f);
  float mean = msum * inv_n;
  float var  = e2 * inv_n - mean * mean;
  float sv   = gamma[c] * rsqrtf(var + 1e-5f);
  ws[ST1 + c]      = sv;
  ws[ST1 + 16 + c] = beta[c] - mean * sv;
}

// BN2 finalize, one block per channel (reduces P2 [1024][64]).
__global__ __launch_bounds__(256) void k_stats2(
    const float* __restrict__ gamma, const float* __restrict__ beta,
    float* __restrict__ ws, int nch, int part_off, int st_off, float inv_n)
{
  const int c = blockIdx.x, tid = threadIdx.x;
  const int w = tid >> 6, lane = tid & 63;
  __shared__ float rs[4], rq[4];
  float s = 0.f, q = 0.f;
#pragma unroll 4
  for (int i = tid; i < NPART; i += 256) {
    s += ws[part_off + i * 2 * nch + c];
    q += ws[part_off + i * 2 * nch + nch + c];
  }
#pragma unroll
  for (int d = 1; d < 64; d <<= 1) {
    s += __shfl_xor(s, d);
    q += __shfl_xor(q, d);
  }
  if (lane == 0) { rs[w] = s; rq[w] = q; }
  __syncthreads();
  if (tid == 0) {
    float st = rs[0] + rs[1] + rs[2] + rs[3];
    float qt = rq[0] + rq[1] + rq[2] + rq[3];
    float mean = st * inv_n;
    float var  = qt * inv_n - mean * mean;
    float sv   = gamma[c] * rsqrtf(var + 1e-5f);
    ws[st_off + c]       = sv;
    ws[st_off + nch + c] = beta[c] - mean * sv;
  }
}

// K3: conv1(MFMA,folded,packed-frag) + conv2(swapped, raw) stats.
// conv2 D: col(b)=pix, row(4q+r)=ch(nt half).
__global__ __launch_bounds__(256) void k3_conv2_stats(
    const float* __restrict__ x, const float* __restrict__ w1,
    const float* __restrict__ w2, float* __restrict__ ws)
{
  __shared__ alignas(16) short sb[16 * 16 * 2 * 16 + 32];
  __shared__ alignas(16) short a1h[4 * 2 * A1B];
  __shared__ float redf[256];
  const int tid = threadIdx.x, w = tid >> 6, lane = tid & 63;
  const int b = lane & 15, q = lane >> 4;
  build_sb(x, sb, tid, blockIdx.x);
  bf16x8 a1f = conv1_afrag(w1, ws[ST1 + b], b, q);
  f32x4 c1i;
#pragma unroll
  for (int r = 0; r < 4; ++r) c1i[r] = ws[ST1 + 16 + 4 * q + r];
  bf16x8 b2h[4];   // A-side: [ks][nt], m=ch=b, raw
#pragma unroll
  for (int ks = 0; ks < 2; ++ks)
#pragma unroll
    for (int nt = 0; nt < 2; ++nt) {
      bf16x8 vh;
#pragma unroll
      for (int j = 0; j < 8; ++j) {
        int kk = 8 * (q & 1) + j, dj = q >> 1;
        vh[j] = (short)f2bf(w2[(nt * 16 + b) * 64 + kk * 4 + ks * 2 + dj]);
      }
      b2h[ks * 2 + nt] = vh;
    }
  const float vb = (b < 13) ? 1.f : 0.f;
  const int colAr = (b + (q >> 1) < 15) ? (b + (q >> 1)) : 15;
  const int offAl = colAr * A1S + 8 * (q & 1);
  __syncthreads();

  float s2r[2][4] = {{0.f,0.f,0.f,0.f},{0.f,0.f,0.f,0.f}};
  float q2r[2][4] = {{0.f,0.f,0.f,0.f},{0.f,0.f,0.f,0.f}};
  short* ph = a1h + w * (2 * A1B);
#pragma unroll 1
  for (int t = 0; t < 4; ++t) {
    const short* sbi = sb + (w * 4 + t) * 512;
    conv1_mfma(sbi, ph, 0, b, q, a1f, c1i);
    __builtin_amdgcn_wave_barrier();
#pragma unroll 1
    for (int i = 0; i < 13; ++i) {
      conv1_mfma(sbi, ph, i + 1, b, q, a1f, c1i);
      __builtin_amdgcn_wave_barrier();
      bf16x8 ah0 = *(const bf16x8*)(ph + (i & 1) * A1B + offAl);
      bf16x8 ah1 = *(const bf16x8*)(ph + ((i + 1) & 1) * A1B + offAl);
      f32x4 acc2[2] = {{0.f,0.f,0.f,0.f},{0.f,0.f,0.f,0.f}};
#pragma unroll
      for (int nt = 0; nt < 2; ++nt) {
        acc2[nt] = __builtin_amdgcn_mfma_f32_16x16x32_bf16(b2h[nt], ah0, acc2[nt], 0, 0, 0);
        acc2[nt] = __builtin_amdgcn_mfma_f32_16x16x32_bf16(b2h[2 + nt], ah1, acc2[nt], 0, 0, 0);
      }
#pragma unroll
      for (int nt = 0; nt < 2; ++nt)
#pragma unroll
        for (int r = 0; r < 4; ++r) {
          float ym = acc2[nt][r] * vb;
          s2r[nt][r] += ym;
          q2r[nt][r] = fmaf(ym, acc2[nt][r], q2r[nt][r]);
        }
      __builtin_amdgcn_wave_barrier();
    }
  }
  // reduce over the 16 pix-lanes (b); lane b==0 holds ch = nt*16+4q+r
#pragma unroll
  for (int nt = 0; nt < 2; ++nt)
#pragma unroll
    for (int r = 0; r < 4; ++r) {
      float sv = s2r[nt][r], qv = q2r[nt][r];
      sv += __shfl_xor(sv, 1); sv += __shfl_xor(sv, 2);
      sv += __shfl_xor(sv, 4); sv += __shfl_xor(sv, 8);
      qv += __shfl_xor(qv, 1); qv += __shfl_xor(qv, 2);
      qv += __shfl_xor(qv, 4); qv += __shfl_xor(qv, 8);
      if (b == 0) {
        redf[w * 64 + nt * 16 + 4 * q + r]      = sv;
        redf[w * 64 + 32 + nt * 16 + 4 * q + r] = qv;
      }
    }
  __syncthreads();
  if (tid < 64)
    ws[P2_OFF + blockIdx.x * 64 + tid] =
        redf[tid] + redf[64 + tid] + redf[128 + tid] + redf[192 + tid];
}

// K5: conv1(MFMA,folded,packed-frag) + conv2(UN-swapped, bn2-folded):
// D lane(b)=ch, rows(4q+r)=pix. a2 staged per-wave in LDS [16pix][32ch]
// then ONE coalesced 832B burst per row. Syrk frags direct from pk regs;
// S2 via mfma(ones, xf).
__global__ __launch_bounds__(256) void k5_a2(
    const float* __restrict__ x, const float* __restrict__ w1,
    const float* __restrict__ w2, float* __restrict__ ws,
    short* __restrict__ a2g, float* __restrict__ parts)
{
  __shared__ alignas(16) short sb[16 * 16 * 2 * 16 + 32];  // reused as redc
  __shared__ alignas(16) short a1h[4 * 2 * A1B];
  __shared__ alignas(16) short a2st[4 * 512];    // per-wave [16pix][32ch]
  __shared__ float s2red[4 * 32];
  const int tid = threadIdx.x, w = tid >> 6, lane = tid & 63;
  const int b = lane & 15, q = lane >> 4;
  build_sb(x, sb, tid, blockIdx.x);
  bf16x8 a1f = conv1_afrag(w1, ws[ST1 + b], b, q);
  f32x4 c1i;
#pragma unroll
  for (int r = 0; r < 4; ++r) c1i[r] = ws[ST1 + 16 + 4 * q + r];
  bf16x8 b2h[4];   // B-side: [ks][nt], n=ch=b, scaled by s2[nt*16+b]
#pragma unroll
  for (int ks = 0; ks < 2; ++ks)
#pragma unroll
    for (int nt = 0; nt < 2; ++nt) {
      float rs2b = ws[ST2 + nt * 16 + b];
      bf16x8 vh;
#pragma unroll
      for (int j = 0; j < 8; ++j) {
        int kk = 8 * (q & 1) + j, dj = q >> 1;
        vh[j] = (short)f2bf(w2[(nt * 16 + b) * 64 + kk * 4 + ks * 2 + dj] * rs2b);
      }
      b2h[ks * 2 + nt] = vh;
    }
  // C-init: D rows are PIXELS (mask 4q+r>=13), bias t2 indexed by CH=nt*16+b.
  f32x4 c2i[2];
#pragma unroll
  for (int nt = 0; nt < 2; ++nt) {
    float t2b = ws[ST2 + 32 + nt * 16 + b];
#pragma unroll
    for (int r = 0; r < 4; ++r)
      c2i[nt][r] = (4 * q + r < 13) ? t2b : -1e30f;
  }
  const int colAr = (b + (q >> 1) < 15) ? (b + (q >> 1)) : 15;
  const int offAl = colAr * A1S + 8 * (q & 1);
  const u32x4 ou = {0x3F803F80u, 0x3F803F80u, 0x3F803F80u, 0x3F803F80u};
  const bf16x8 ones = __builtin_bit_cast(bf16x8, ou);
  __syncthreads();

  f32x4 accT0 = {0.f,0.f,0.f,0.f}, accT1 = {0.f,0.f,0.f,0.f},
        accT2 = {0.f,0.f,0.f,0.f};
  f32x4 accS0 = {0.f,0.f,0.f,0.f}, accS1 = {0.f,0.f,0.f,0.f};
  short* ph = a1h + w * (2 * A1B);
  short* st = a2st + w * 512;
#pragma unroll 1
  for (int t = 0; t < 4; ++t) {
    const int img = blockIdx.x * 16 + w * 4 + t;
    const short* sbi = sb + (w * 4 + t) * 512;
    short* gb = a2g + (size_t)img * 5408;
    conv1_mfma(sbi, ph, 0, b, q, a1f, c1i);
    __builtin_amdgcn_wave_barrier();
    uint2 pkp[2];
#pragma unroll 1
    for (int i = 0; i < 13; ++i) {
      conv1_mfma(sbi, ph, i + 1, b, q, a1f, c1i);
      __builtin_amdgcn_wave_barrier();
      bf16x8 ah0 = *(const bf16x8*)(ph + (i & 1) * A1B + offAl);
      bf16x8 ah1 = *(const bf16x8*)(ph + ((i + 1) & 1) * A1B + offAl);
      uint2 pkc[2];
#pragma unroll
      for (int nt = 0; nt < 2; ++nt) {
        f32x4 acc2 = c2i[nt];
        acc2 = __builtin_amdgcn_mfma_f32_16x16x32_bf16(ah0, b2h[nt], acc2, 0, 0, 0);
        acc2 = __builtin_amdgcn_mfma_f32_16x16x32_bf16(ah1, b2h[2 + nt], acc2, 0, 0, 0);
        float v0 = acc2[0] > 0.f ? acc2[0] : 0.f;
        float v1 = acc2[1] > 0.f ? acc2[1] : 0.f;
        float v2 = acc2[2] > 0.f ? acc2[2] : 0.f;
        float v3 = acc2[3] > 0.f ? acc2[3] : 0.f;
        uint2 pk;
        pk.x = pkbf(v0, v1);
        pk.y = pkbf(v2, v3);
        // stage [pix 4q+r][ch nt*16+b]; invalid pix rows hold 0 (not copied)
        short* sp = st + nt * 16 + b;
        sp[(4 * q + 0) * 32] = (short)pk.x;
        sp[(4 * q + 1) * 32] = (short)(pk.x >> 16);
        sp[(4 * q + 2) * 32] = (short)pk.y;
        sp[(4 * q + 3) * 32] = (short)(pk.y >> 16);
        pkc[nt] = pk;
      }
      __builtin_amdgcn_wave_barrier();
      if (lane < 52) {   // one coalesced 832B burst: 13 pix x 32 ch
        bf16x8 vv = *(const bf16x8*)(st + lane * 8);
        *(bf16x8*)(gb + (size_t)i * 416 + lane * 8) = vv;
      }
      if (i & 1) {       // syrk over row pair (i-1, i), frags from registers
        bf16x8 xf0 = mkfrag(pkp[0], pkc[0]);
        bf16x8 xf1 = mkfrag(pkp[1], pkc[1]);
        accT0 = __builtin_amdgcn_mfma_f32_16x16x32_bf16(xf0, xf0, accT0, 0, 0, 0);
        accT1 = __builtin_amdgcn_mfma_f32_16x16x32_bf16(xf0, xf1, accT1, 0, 0, 0);
        accT2 = __builtin_amdgcn_mfma_f32_16x16x32_bf16(xf1, xf1, accT2, 0, 0, 0);
        accS0 = __builtin_amdgcn_mfma_f32_16x16x32_bf16(ones, xf0, accS0, 0, 0, 0);
        accS1 = __builtin_amdgcn_mfma_f32_16x16x32_bf16(ones, xf1, accS1, 0, 0, 0);
      } else {
        pkp[0] = pkc[0];
        pkp[1] = pkc[1];
      }
      __builtin_amdgcn_wave_barrier();
    }
    // leftover row 12 (parity 0, held in pkp): pair with zeros
    {
      uint2 zz; zz.x = 0u; zz.y = 0u;
      bf16x8 xf0 = mkfrag(pkp[0], zz);
      bf16x8 xf1 = mkfrag(pkp[1], zz);
      accT0 = __builtin_amdgcn_mfma_f32_16x16x32_bf16(xf0, xf0, accT0, 0, 0, 0);
      accT1 = __builtin_amdgcn_mfma_f32_16x16x32_bf16(xf0, xf1, accT1, 0, 0, 0);
      accT2 = __builtin_amdgcn_mfma_f32_16x16x32_bf16(xf1, xf1, accT2, 0, 0, 0);
      accS0 = __builtin_amdgcn_mfma_f32_16x16x32_bf16(ones, xf0, accS0, 0, 0, 0);
      accS1 = __builtin_amdgcn_mfma_f32_16x16x32_bf16(ones, xf1, accS1, 0, 0, 0);
    }
  }
  // S2: all rows of accS are identical column sums; col(lane&15)=ch.
  if (q == 0) {
    s2red[w * 32 + b]      = accS0[0];
    s2red[w * 32 + 16 + b] = accS1[0];
  }
  float* redc = (float*)sb;   // wave w writes only into its own quarter
  __syncthreads();            // all sb reads done
#pragma unroll
  for (int rr = 0; rr < 4; ++rr) {
    int m = 4 * q + rr;
    redc[w * 1024 + 0   + m * 16 + b] = accT0[rr];
    redc[w * 1024 + 256 + m * 16 + b] = accT1[rr];
    redc[w * 1024 + 512 + m * 16 + b] = accT2[rr];
  }
  __syncthreads();
  for (int e = tid; e < 768; e += 256)
    parts[blockIdx.x * 800 + e] =
        redc[e] + redc[1024 + e] + redc[2048 + e] + redc[3072 + e];
  if (tid < 32)
    parts[blockIdx.x * 800 + 768 + tid] =
        s2red[tid] + s2red[32 + tid] + s2red[64 + tid] + s2red[96 + tid];
}

// Reduce C2/S2 block partials: one block per entry e in [0,800).
__global__ __launch_bounds__(256) void k_statsC(
    const float* __restrict__ parts, float* __restrict__ ws)
{
  const int e = blockIdx.x, tid = threadIdx.x;
  const int w = tid >> 6, lane = tid & 63;
  __shared__ float rs[4];
  float s = 0.f;
#pragma unroll 4
  for (int i = tid; i < 1024; i += 256) s += parts[i * 800 + e];
#pragma unroll
  for (int d = 1; d < 64; d <<= 1) s += __shfl_xor(s, d);
  if (lane == 0) rs[w] = s;
  __syncthreads();
  if (tid == 0) ws[C2R_OFF + e] = rs[0] + rs[1] + rs[2] + rs[3];
}

// BN3 finalize from S2/C2: mean=w3^T S2/N, E[y3^2]=w3^T C2 w3 /N.
__global__ __launch_bounds__(64) void k_stats3n(
    const float* __restrict__ w3, const float* __restrict__ gamma,
    const float* __restrict__ beta, float* __restrict__ ws)
{
  const int c3 = threadIdx.x;
  if (c3 >= 64) return;
  const float* C2R = ws + C2R_OFF;
  float wr[32];
#pragma unroll
  for (int k = 0; k < 32; ++k) wr[k] = w3[c3 * 32 + k];
  const float inv_n = 1.0f / (16384.0f * 169.0f);
  float msum = 0.f;
#pragma unroll
  for (int k = 0; k < 32; ++k) msum += wr[k] * C2R[768 + k];
  float e2 = 0.f;
  for (int a = 0; a < 16; ++a)
#pragma unroll
    for (int bb = 0; bb < 16; ++bb) {
      e2 += wr[a] * wr[bb] * C2R[a * 16 + bb];                  // T00
      e2 += wr[16 + a] * wr[16 + bb] * C2R[512 + a * 16 + bb];  // T11
      e2 += 2.f * wr[a] * wr[16 + bb] * C2R[256 + a * 16 + bb]; // T01
    }
  float mean = msum * inv_n;
  float var  = e2 * inv_n - mean * mean;
  float sv   = gamma[c3] * rsqrtf(var + 1e-5f);
  ws[ST3 + c3]      = sv;
  ws[ST3 + 64 + c3] = beta[c3] - mean * sv;
}

// K0: pack fc_w into the register-direct FC order:
// fcB[((p*2+h)*64 + lane)*4 + u]; lane=(q<<4)|b; jj=b; k=8q+e elements with
// c3(e) = h*32 + (e>>2)*16 + 4q + (e&3); F_orig = c3*169 + p.
__global__ __launch_bounds__(256) void k0_fcB(
    const float* __restrict__ fcw, unsigned int* __restrict__ fcB)
{
  int f = blockIdx.x * 256 + threadIdx.x;   // FCB_N = 338*256 exactly
  int u = f & 3, lane = (f >> 2) & 63, h = (f >> 8) & 1, p = f >> 9;
  int b = lane & 15, q = lane >> 4;
  unsigned lo = 0, hi = 0;
  if (b < 10) {
    int c30 = h * 32 + (u >> 1) * 16 + 4 * q + 2 * (u & 1);
    lo = f2bf(fcw[b * 10816 + c30 * 169 + p]);
    hi = f2bf(fcw[b * 10816 + (c30 + 1) * 169 + p]);
  }
  fcB[f] = lo | (hi << 16);
}

// K7: conv3 operand-swapped (A=w3 m=c3, B=a2^T n=img) + FC direct from regs.
__global__ __launch_bounds__(256) void k7_fc(
    const short* __restrict__ a2g, const float* __restrict__ w3,
    const float* __restrict__ fcb, const float* __restrict__ ws,
    float* __restrict__ out)
{
  __shared__ float redf7[1024];
  const int tid = threadIdx.x, w = tid >> 6, lane = tid & 63;
  const int b = lane & 15, q = lane >> 4;
  bf16x8 b3h[4];     // A-side: m=c3=nt*16+b, k=ch 8q+j, scaled by s3[c3]
  f32x4 c3i[4];      // C-init: rows are c3-local 4q+r -> t3[nt*16+4q+r]
#pragma unroll
  for (int nt = 0; nt < 4; ++nt) {
    float s3 = ws[ST3 + nt * 16 + b];
    bf16x8 vh;
#pragma unroll
    for (int j = 0; j < 8; ++j)
      vh[j] = (short)f2bf(w3[(nt * 16 + b) * 32 + 8 * q + j] * s3);
    b3h[nt] = vh;
#pragma unroll
    for (int r = 0; r < 4; ++r)
      c3i[nt][r] = ws[ST3 + 64 + nt * 16 + 4 * q + r];
  }
  const bf16x8* fcB = (const bf16x8*)ws;
  const short* abase = a2g + (size_t)(blockIdx.x * 16 + b) * 5408 + 8 * q;
  const int p0 = (w * 169) >> 2, p1 = ((w + 1) * 169) >> 2;
  f32x4 aF0 = {0.f, 0.f, 0.f, 0.f}, aF1 = {0.f, 0.f, 0.f, 0.f};
  bf16x8 vpre = *(const bf16x8*)(abase + p0 * 32);
  bf16x8 bw0 = fcB[(p0 * 2 + 0) * 64 + lane];
  bf16x8 bw1 = fcB[(p0 * 2 + 1) * 64 + lane];
#pragma unroll 1
  for (int p = p0; p < p1; ++p) {
    bf16x8 vc = vpre, f0 = bw0, f1 = bw1;
    if (p + 1 < p1) {
      vpre = *(const bf16x8*)(abase + (p + 1) * 32);
      bw0 = fcB[((p + 1) * 2 + 0) * 64 + lane];
      bw1 = fcB[((p + 1) * 2 + 1) * 64 + lane];
    }
    uint2 pkc[4];
#pragma unroll
    for (int nt = 0; nt < 4; ++nt) {
      f32x4 acc3 = c3i[nt];
      acc3 = __builtin_amdgcn_mfma_f32_16x16x32_bf16(b3h[nt], vc, acc3, 0, 0, 0);
      float v0 = acc3[0] > 0.f ? acc3[0] : 0.f;
      float v1 = acc3[1] > 0.f ? acc3[1] : 0.f;
      float v2 = acc3[2] > 0.f ? acc3[2] : 0.f;
      float v3 = acc3[3] > 0.f ? acc3[3] : 0.f;
      pkc[nt].x = pkbf(v0, v1);
      pkc[nt].y = pkbf(v2, v3);
    }
    aF0 = __builtin_amdgcn_mfma_f32_16x16x32_bf16(mkfrag(pkc[0], pkc[1]), f0, aF0, 0, 0, 0);
    aF1 = __builtin_amdgcn_mfma_f32_16x16x32_bf16(mkfrag(pkc[2], pkc[3]), f1, aF1, 0, 0, 0);
  }
  // FC D: col(lane&15)=jj=b, row(4q+r)=img-slot. Reduce the 4 pix-chunk waves.
#pragma unroll
  for (int r = 0; r < 4; ++r)
    redf7[w * 256 + (4 * q + r) * 16 + b] = aF0[r] + aF1[r];
  __syncthreads();
  if (tid < 160) {
    int img = tid / 10, jj = tid - img * 10;
    float s = redf7[img * 16 + jj] + redf7[256 + img * 16 + jj] +
              redf7[512 + img * 16 + jj] + redf7[768 + img * 16 + jj];
    out[(blockIdx.x * 16 + img) * 10 + jj] = s + fcb[jj];
  }
}

extern "C" void kernel_launch(void* const* d_in, const int* in_sizes, int n_in,
                              void* d_out, int out_size, void* d_ws, size_t ws_size,
                              hipStream_t stream) {
  (void)in_sizes; (void)n_in; (void)out_size; (void)ws_size;
  const float* x   = (const float*)d_in[0];
  const float* w1  = (const float*)d_in[1];
  const float* w2  = (const float*)d_in[2];
  const float* w3  = (const float*)d_in[3];
  const float* g1  = (const float*)d_in[4];
  const float* b1  = (const float*)d_in[5];
  const float* g2  = (const float*)d_in[6];
  const float* b2  = (const float*)d_in[7];
  const float* g3  = (const float*)d_in[8];
  const float* b3  = (const float*)d_in[9];
  const float* fcw = (const float*)d_in[10];
  const float* fcb = (const float*)d_in[11];
  float* out = (float*)d_out;
  float* ws  = (float*)d_ws;
  short* a2g = (short*)((char*)d_ws + A2G_BYTE);
  float* parts = ws + C2P_OFF;

  k1_xsyrk<<<1024, 256, 0, stream>>>(x, parts);
  k_stats1a<<<256, 256, 0, stream>>>(parts, ws);
  k_stats1b<<<1, 64, 0, stream>>>(w1, g1, b1, ws);
  k3_conv2_stats<<<1024, 256, 0, stream>>>(x, w1, w2, ws);
  k_stats2<<<32, 256, 0, stream>>>(g2, b2, ws, 32, P2_OFF, ST2,
                                   1.0f / (16384.0f * 169.0f));
  k5_a2<<<1024, 256, 0, stream>>>(x, w1, w2, ws, a2g, parts);
  k_statsC<<<800, 256, 0, stream>>>(parts, ws);
  k_stats3n<<<1, 64, 0, stream>>>(w3, g3, b3, ws);
  k0_fcB<<<FCB_N / 256, 256, 0, stream>>>(fcw, (unsigned int*)ws);
  k7_fc<<<1024, 256, 0, stream>>>(a2g, w3, fcb, ws, out);
}

// Round 13
// 244.749 us; speedup vs baseline: 1.2089x; 1.0053x over previous
//
#include <hip/hip_runtime.h>

// ---------------------------------------------------------------------------
// LocallyConnectedNN: x[16384,256] -> conv3x3(1->16)+BN+ReLU -> conv2x2(16->32)
// +BN+ReLU -> conv1x1(32->64)+BN+ReLU -> FC(10816->10).
// Round 21: conv1 fragment load made BRANCH-FREE (round 20 = 246.0us proved
// instruction removal is the lever; the 3-way q-branch in conv1_mfma was the
// biggest remaining per-row overhead). All lanes load 4 words uniformly
// (2 adjacent pairs -> ds_read2_b32): rA = r + selA (selA=2 for q==1 lanes,
// else 0), rB = r+1. Zero-A-weight slots tolerate any FINITE garbage (sb is
// all finite bf16): q0 real rows r,r+1; q1 row r+2 + ignored r+1; q>=2 all
// ignored. Exec-mask dance deleted from 14 calls x 4 img per wave in k3+k5.
// Bit-identical accumulation (0 x finite = 0). Everything else = round 20.
// ---------------------------------------------------------------------------

#define NPART 1024
#define P2_OFF 32768      // [1024][64] conv2 stats partials
#define ST_OFF 229376     // s1[16] t1[16] s2[32] t2[32] s3[64] t3[64]
#define ST1 ST_OFF
#define ST2 (ST_OFF + 32)
#define ST3 (ST_OFF + 96)
#define C2R_OFF 230400    // reduced [768 C2 tiles | 32 S2]
#define C1R_OFF 231424    // reduced x-patch Cext [16x16]
#define C2P_OFF 262144    // block partials (1MB..): k1 [1024][256], k5 [1024][800]
#define A2G_BYTE 5242880ull // a2 cache: [img][13 i][13 pix][32 ch] bf16, 177MB
#define FCB_N 86528       // fcB u32: [169 p][2 h][64 lane][4 u]
#define A1S 24            // a1h LDS row stride (shorts)
#define A1B 384           // one a1 LDS buffer (16 rows x A1S)

typedef __attribute__((ext_vector_type(8))) short bf16x8;
typedef __attribute__((ext_vector_type(4))) float f32x4;
typedef __attribute__((ext_vector_type(4))) unsigned int u32x4;

__device__ __forceinline__ unsigned int f2bf(float f) {
  unsigned int u = __float_as_uint(f);
  return (u + 0x7fffu + ((u >> 16) & 1u)) >> 16;   // RTNE bf16 bits
}
// pack two floats to bf16x2 (round-half-up): 2 adds + 1 v_perm_b32
__device__ __forceinline__ unsigned int pkbf(float a, float b) {
  unsigned ua = __float_as_uint(a) + 0x8000u;
  unsigned ub = __float_as_uint(b) + 0x8000u;
  return __builtin_amdgcn_perm(ub, ua, 0x07060302u);
}
__device__ __forceinline__ bf16x8 mkfrag(uint2 a, uint2 b) {
  u32x4 u = {a.x, a.y, b.x, b.y};
  return __builtin_bit_cast(bf16x8, u);
}

// conv1 (3x3,1->16)+bn1(folded)+relu for output row r, swapped operands:
// A = w1*rs1 (m=ch, PERMUTED k), B = im2row from pre-packed sb.
// BRANCH-FREE: all lanes load 4 words (2 ds_read2_b32). selA = (q==1)?2:0.
// q0: rows r,r+1 (weights w0..w5); q1: row r+2 real (w6..w8) + row r+1
// garbage x zero weights; q>=2: garbage x zero weights. All finite.
// D: col(lane&15)=j, row(4q+r)=ch -> ph[j][ch] write = 1 ds_write_b64.
__device__ __forceinline__ void conv1_mfma(
    const short* __restrict__ sbi,   // [16 rows][2 cp][16 cols] bf16 (+pad)
    short* ph_buf,                   // [2 bufs][16 j][A1S ch]
    int r, int b, int q, int selA, bf16x8 a1f, f32x4 c1i)
{
  const unsigned* base = (const unsigned*)sbi;
  const int cw = (b & 1) * 8 + (b >> 1);   // cp*8 + word; row stride 16 u32
  const unsigned* rA = base + (r + selA) * 16 + cw;
  const unsigned* rB = base + (r + 1) * 16 + cw;
  bf16x8 bf;
  unsigned* bu = (unsigned*)&bf;
  bu[0] = rA[0];
  bu[1] = rA[1];
  bu[2] = rB[0];
  bu[3] = rB[1];
  f32x4 acc = c1i;
  acc = __builtin_amdgcn_mfma_f32_16x16x32_bf16(a1f, bf, acc, 0, 0, 0);
  float v0 = acc[0] > 0.f ? acc[0] : 0.f;
  float v1 = acc[1] > 0.f ? acc[1] : 0.f;
  float v2 = acc[2] > 0.f ? acc[2] : 0.f;
  float v3 = acc[3] > 0.f ? acc[3] : 0.f;
  uint2 pk;
  pk.x = pkbf(v0, v1);
  pk.y = pkbf(v2, v3);
  *(uint2*)(ph_buf + (r & 1) * A1B + b * A1S + 4 * q) = pk;
}

// conv1 A-frag, PERMUTED to match conv1_mfma's B layout:
// q0: {w0,w1,w2,0,w3,w4,w5,0}; q1: {w6,w7,w8,0,0,0,0,0}; q>=2: zeros.
__device__ __forceinline__ bf16x8 conv1_afrag(const float* w1, float rs1b,
                                              int b, int q) {
  bf16x8 v = {0, 0, 0, 0, 0, 0, 0, 0};
  if (q == 0) {
#pragma unroll
    for (int j = 0; j < 3; ++j) {
      v[j]     = (short)f2bf(w1[b * 9 + j] * rs1b);
      v[4 + j] = (short)f2bf(w1[b * 9 + 3 + j] * rs1b);
    }
  } else if (q == 1) {
#pragma unroll
    for (int j = 0; j < 3; ++j)
      v[j] = (short)f2bf(w1[b * 9 + 6 + j] * rs1b);
  }
  return v;
}

// Build dual-copy packed x in LDS: sb[img][row][cp][16], cp1 = +1 col shift.
// 256 threads; caller syncs after.
__device__ __forceinline__ void build_sb(const float* __restrict__ x,
                                         short* sb, int tid, int nblk16) {
  {
    const float4* xs = (const float4*)(x + (size_t)nblk16 * (16 * 256));
    for (int e = tid; e < 16 * 64; e += 256) {
      float4 v = xs[e];
      int img = e >> 6, row = (e >> 2) & 15, g = e & 3;
      uint2 pk;
      pk.x = pkbf(v.x, v.y);
      pk.y = pkbf(v.z, v.w);
      *(uint2*)(sb + ((img * 16 + row) * 2 + 0) * 16 + 4 * g) = pk;
    }
    if (tid < 16) ((unsigned*)(sb + 16 * 16 * 2 * 16))[tid] = 0u;  // pad
  }
  __syncthreads();
  {
    int img = tid >> 4, row = tid & 15;
    const unsigned* s0 = (const unsigned*)(sb + ((img * 16 + row) * 2 + 0) * 16);
    unsigned* s1 = (unsigned*)(sb + ((img * 16 + row) * 2 + 1) * 16);
    unsigned wprev = s0[0];
#pragma unroll
    for (int c = 0; c < 8; ++c) {
      unsigned wnext = (c < 7) ? s0[c + 1] : 0u;
      s1[c] = __builtin_amdgcn_perm(wnext, wprev, 0x05040302u);
      wprev = wnext;
    }
  }
}

// K1: x patch-covariance via MFMA syrk (own sb copy, unchanged layout).
__global__ __launch_bounds__(256) void k1_xsyrk(
    const float* __restrict__ x, float* __restrict__ parts)
{
  __shared__ alignas(16) short sb[16 * 16 * 2 * 16 + 32];
  const int tid = threadIdx.x, w = tid >> 6, lane = tid & 63;
  const int b = lane & 15, q = lane >> 4;
  build_sb(x, sb, tid, blockIdx.x);
  __syncthreads();
  const int di = (b < 9) ? (b / 3) : 0;
  const int dj = (b < 9) ? (b - di * 3) : 0;
  const int cp = dj & 1, dsh = dj >> 1;
  const int h = q >> 1, jb = (q & 1) * 8;
  const int wb = (jb >> 1) + dsh;
  f32x4 acc = {0.f, 0.f, 0.f, 0.f};
#pragma unroll 1
  for (int t = 0; t < 4; ++t) {
    const int ib = (w * 4 + t) * 16;
#pragma unroll 1
    for (int s = 0; s < 7; ++s) {
      bf16x8 af;
      unsigned* au = (unsigned*)&af;
      if (b < 9) {
        const unsigned* sr = (const unsigned*)(
            sb + ((ib + (2 * s + h + di)) * 2 + cp) * 16);
        au[0] = sr[wb];
        au[1] = sr[wb + 1];
        au[2] = sr[wb + 2];
        au[3] = (jb == 0) ? sr[wb + 3] : 0u;   // out-col >= 14 -> zero slot
      } else if (b == 9) {
#pragma unroll
        for (int cc = 0; cc < 4; ++cc) {
          unsigned lo = (jb + 2 * cc     < 14) ? 0x3F80u : 0u;
          unsigned hi = (jb + 2 * cc + 1 < 14) ? 0x3F800000u : 0u;
          au[cc] = lo | hi;
        }
      } else {
#pragma unroll
        for (int cc = 0; cc < 4; ++cc) au[cc] = 0u;
      }
      acc = __builtin_amdgcn_mfma_f32_16x16x32_bf16(af, af, acc, 0, 0, 0);
    }
  }
  __syncthreads();                 // done reading sb; reuse as reduce buffer
  float* redc = (float*)sb;
#pragma unroll
  for (int rr = 0; rr < 4; ++rr)
    redc[w * 256 + (4 * q + rr) * 16 + b] = acc[rr];
  __syncthreads();
  parts[blockIdx.x * 256 + tid] =
      redc[tid] + redc[256 + tid] + redc[512 + tid] + redc[768 + tid];
}

// Reduce k1 partials [1024][256] -> Cext[256].
__global__ __launch_bounds__(256) void k_stats1a(
    const float* __restrict__ parts, float* __restrict__ ws)
{
  const int e = blockIdx.x, tid = threadIdx.x;
  const int w = tid >> 6, lane = tid & 63;
  __shared__ float rs[4];
  float s = 0.f;
#pragma unroll 4
  for (int i = tid; i < 1024; i += 256) s += parts[i * 256 + e];
#pragma unroll
  for (int d = 1; d < 64; d <<= 1) s += __shfl_xor(s, d);
  if (lane == 0) rs[w] = s;
  __syncthreads();
  if (tid == 0) ws[C1R_OFF + e] = rs[0] + rs[1] + rs[2] + rs[3];
}

// BN1 finalize from Cext: mean = w^T S /N, E[y^2] = w^T C w /N.
__global__ __launch_bounds__(64) void k_stats1b(
    const float* __restrict__ w1, const float* __restrict__ gamma,
    const float* __restrict__ beta, float* __restrict__ ws)
{
  const int c = threadIdx.x;
  if (c >= 16) return;
  const float* C = ws + C1R_OFF;
  float wr[9];
#pragma unroll
  for (int p = 0; p < 9; ++p) wr[p] = w1[c * 9 + p];
  float msum = 0.f;
#pragma unroll
  for (int p = 0; p < 9; ++p) msum += wr[p] * C[9 * 16 + p];
  float e2 = 0.f;
#pragma unroll
  for (int a = 0; a < 9; ++a)
#pragma unroll
    for (int bb = 0; bb < 9; ++bb)
      e2 += wr[a] * wr[bb] * C[a * 16 + bb];
  const float inv_n = 1.0f / (16384.0f * 196.0f);
  float mean = msum * inv_n;
  float var  = e2 * inv_n - mean * mean;
  float sv   = gamma[c] * rsqrtf(var + 1e-5f);
  ws[ST1 + c]      = sv;
  ws[ST1 + 16 + c] = beta[c] - mean * sv;
}

// BN2 finalize, one block per channel (reduces P2 [1024][64]).
__global__ __launch_bounds__(256) void k_stats2(
    const float* __restrict__ gamma, const float* __restrict__ beta,
    float* __restrict__ ws, int nch, int part_off, int st_off, float inv_n)
{
  const int c = blockIdx.x, tid = threadIdx.x;
  const int w = tid >> 6, lane = tid & 63;
  __shared__ float rs[4], rq[4];
  float s = 0.f, q = 0.f;
#pragma unroll 4
  for (int i = tid; i < NPART; i += 256) {
    s += ws[part_off + i * 2 * nch + c];
    q += ws[part_off + i * 2 * nch + nch + c];
  }
#pragma unroll
  for (int d = 1; d < 64; d <<= 1) {
    s += __shfl_xor(s, d);
    q += __shfl_xor(q, d);
  }
  if (lane == 0) { rs[w] = s; rq[w] = q; }
  __syncthreads();
  if (tid == 0) {
    float st = rs[0] + rs[1] + rs[2] + rs[3];
    float qt = rq[0] + rq[1] + rq[2] + rq[3];
    float mean = st * inv_n;
    float var  = qt * inv_n - mean * mean;
    float sv   = gamma[c] * rsqrtf(var + 1e-5f);
    ws[st_off + c]       = sv;
    ws[st_off + nch + c] = beta[c] - mean * sv;
  }
}

// K3: conv1(MFMA,folded,branch-free frag) + conv2(swapped, raw) stats.
// conv2 D: col(b)=pix, row(4q+r)=ch(nt half).
__global__ __launch_bounds__(256) void k3_conv2_stats(
    const float* __restrict__ x, const float* __restrict__ w1,
    const float* __restrict__ w2, float* __restrict__ ws)
{
  __shared__ alignas(16) short sb[16 * 16 * 2 * 16 + 32];
  __shared__ alignas(16) short a1h[4 * 2 * A1B];
  __shared__ float redf[256];
  const int tid = threadIdx.x, w = tid >> 6, lane = tid & 63;
  const int b = lane & 15, q = lane >> 4;
  build_sb(x, sb, tid, blockIdx.x);
  bf16x8 a1f = conv1_afrag(w1, ws[ST1 + b], b, q);
  f32x4 c1i;
#pragma unroll
  for (int r = 0; r < 4; ++r) c1i[r] = ws[ST1 + 16 + 4 * q + r];
  bf16x8 b2h[4];   // A-side: [ks][nt], m=ch=b, raw
#pragma unroll
  for (int ks = 0; ks < 2; ++ks)
#pragma unroll
    for (int nt = 0; nt < 2; ++nt) {
      bf16x8 vh;
#pragma unroll
      for (int j = 0; j < 8; ++j) {
        int kk = 8 * (q & 1) + j, dj = q >> 1;
        vh[j] = (short)f2bf(w2[(nt * 16 + b) * 64 + kk * 4 + ks * 2 + dj]);
      }
      b2h[ks * 2 + nt] = vh;
    }
  const float vb = (b < 13) ? 1.f : 0.f;
  const int colAr = (b + (q >> 1) < 15) ? (b + (q >> 1)) : 15;
  const int offAl = colAr * A1S + 8 * (q & 1);
  const int selA = (q == 1) ? 2 : 0;
  __syncthreads();

  float s2r[2][4] = {{0.f,0.f,0.f,0.f},{0.f,0.f,0.f,0.f}};
  float q2r[2][4] = {{0.f,0.f,0.f,0.f},{0.f,0.f,0.f,0.f}};
  short* ph = a1h + w * (2 * A1B);
#pragma unroll 1
  for (int t = 0; t < 4; ++t) {
    const short* sbi = sb + (w * 4 + t) * 512;
    conv1_mfma(sbi, ph, 0, b, q, selA, a1f, c1i);
    __builtin_amdgcn_wave_barrier();
#pragma unroll 1
    for (int i = 0; i < 13; ++i) {
      conv1_mfma(sbi, ph, i + 1, b, q, selA, a1f, c1i);
      __builtin_amdgcn_wave_barrier();
      bf16x8 ah0 = *(const bf16x8*)(ph + (i & 1) * A1B + offAl);
      bf16x8 ah1 = *(const bf16x8*)(ph + ((i + 1) & 1) * A1B + offAl);
      f32x4 acc2[2] = {{0.f,0.f,0.f,0.f},{0.f,0.f,0.f,0.f}};
#pragma unroll
      for (int nt = 0; nt < 2; ++nt) {
        acc2[nt] = __builtin_amdgcn_mfma_f32_16x16x32_bf16(b2h[nt], ah0, acc2[nt], 0, 0, 0);
        acc2[nt] = __builtin_amdgcn_mfma_f32_16x16x32_bf16(b2h[2 + nt], ah1, acc2[nt], 0, 0, 0);
      }
#pragma unroll
      for (int nt = 0; nt < 2; ++nt)
#pragma unroll
        for (int r = 0; r < 4; ++r) {
          float ym = acc2[nt][r] * vb;
          s2r[nt][r] += ym;
          q2r[nt][r] = fmaf(ym, acc2[nt][r], q2r[nt][r]);
        }
      __builtin_amdgcn_wave_barrier();
    }
  }
  // reduce over the 16 pix-lanes (b); lane b==0 holds ch = nt*16+4q+r
#pragma unroll
  for (int nt = 0; nt < 2; ++nt)
#pragma unroll
    for (int r = 0; r < 4; ++r) {
      float sv = s2r[nt][r], qv = q2r[nt][r];
      sv += __shfl_xor(sv, 1); sv += __shfl_xor(sv, 2);
      sv += __shfl_xor(sv, 4); sv += __shfl_xor(sv, 8);
      qv += __shfl_xor(qv, 1); qv += __shfl_xor(qv, 2);
      qv += __shfl_xor(qv, 4); qv += __shfl_xor(qv, 8);
      if (b == 0) {
        redf[w * 64 + nt * 16 + 4 * q + r]      = sv;
        redf[w * 64 + 32 + nt * 16 + 4 * q + r] = qv;
      }
    }
  __syncthreads();
  if (tid < 64)
    ws[P2_OFF + blockIdx.x * 64 + tid] =
        redf[tid] + redf[64 + tid] + redf[128 + tid] + redf[192 + tid];
}

// K5: conv1(MFMA,folded,branch-free frag) + conv2(UN-swapped, bn2-folded):
// D lane(b)=ch, rows(4q+r)=pix. a2 staged per-wave in LDS [16pix][32ch]
// then ONE coalesced 832B burst per row. Syrk frags direct from pk regs;
// S2 via mfma(ones, xf).
__global__ __launch_bounds__(256) void k5_a2(
    const float* __restrict__ x, const float* __restrict__ w1,
    const float* __restrict__ w2, float* __restrict__ ws,
    short* __restrict__ a2g, float* __restrict__ parts)
{
  __shared__ alignas(16) short sb[16 * 16 * 2 * 16 + 32];  // reused as redc
  __shared__ alignas(16) short a1h[4 * 2 * A1B];
  __shared__ alignas(16) short a2st[4 * 512];    // per-wave [16pix][32ch]
  __shared__ float s2red[4 * 32];
  const int tid = threadIdx.x, w = tid >> 6, lane = tid & 63;
  const int b = lane & 15, q = lane >> 4;
  build_sb(x, sb, tid, blockIdx.x);
  bf16x8 a1f = conv1_afrag(w1, ws[ST1 + b], b, q);
  f32x4 c1i;
#pragma unroll
  for (int r = 0; r < 4; ++r) c1i[r] = ws[ST1 + 16 + 4 * q + r];
  bf16x8 b2h[4];   // B-side: [ks][nt], n=ch=b, scaled by s2[nt*16+b]
#pragma unroll
  for (int ks = 0; ks < 2; ++ks)
#pragma unroll
    for (int nt = 0; nt < 2; ++nt) {
      float rs2b = ws[ST2 + nt * 16 + b];
      bf16x8 vh;
#pragma unroll
      for (int j = 0; j < 8; ++j) {
        int kk = 8 * (q & 1) + j, dj = q >> 1;
        vh[j] = (short)f2bf(w2[(nt * 16 + b) * 64 + kk * 4 + ks * 2 + dj] * rs2b);
      }
      b2h[ks * 2 + nt] = vh;
    }
  // C-init: D rows are PIXELS (mask 4q+r>=13), bias t2 indexed by CH=nt*16+b.
  f32x4 c2i[2];
#pragma unroll
  for (int nt = 0; nt < 2; ++nt) {
    float t2b = ws[ST2 + 32 + nt * 16 + b];
#pragma unroll
    for (int r = 0; r < 4; ++r)
      c2i[nt][r] = (4 * q + r < 13) ? t2b : -1e30f;
  }
  const int colAr = (b + (q >> 1) < 15) ? (b + (q >> 1)) : 15;
  const int offAl = colAr * A1S + 8 * (q & 1);
  const int selA = (q == 1) ? 2 : 0;
  const u32x4 ou = {0x3F803F80u, 0x3F803F80u, 0x3F803F80u, 0x3F803F80u};
  const bf16x8 ones = __builtin_bit_cast(bf16x8, ou);
  __syncthreads();

  f32x4 accT0 = {0.f,0.f,0.f,0.f}, accT1 = {0.f,0.f,0.f,0.f},
        accT2 = {0.f,0.f,0.f,0.f};
  f32x4 accS0 = {0.f,0.f,0.f,0.f}, accS1 = {0.f,0.f,0.f,0.f};
  short* ph = a1h + w * (2 * A1B);
  short* st = a2st + w * 512;
#pragma unroll 1
  for (int t = 0; t < 4; ++t) {
    const int img = blockIdx.x * 16 + w * 4 + t;
    const short* sbi = sb + (w * 4 + t) * 512;
    short* gb = a2g + (size_t)img * 5408;
    conv1_mfma(sbi, ph, 0, b, q, selA, a1f, c1i);
    __builtin_amdgcn_wave_barrier();
    uint2 pkp[2];
#pragma unroll 1
    for (int i = 0; i < 13; ++i) {
      conv1_mfma(sbi, ph, i + 1, b, q, selA, a1f, c1i);
      __builtin_amdgcn_wave_barrier();
      bf16x8 ah0 = *(const bf16x8*)(ph + (i & 1) * A1B + offAl);
      bf16x8 ah1 = *(const bf16x8*)(ph + ((i + 1) & 1) * A1B + offAl);
      uint2 pkc[2];
#pragma unroll
      for (int nt = 0; nt < 2; ++nt) {
        f32x4 acc2 = c2i[nt];
        acc2 = __builtin_amdgcn_mfma_f32_16x16x32_bf16(ah0, b2h[nt], acc2, 0, 0, 0);
        acc2 = __builtin_amdgcn_mfma_f32_16x16x32_bf16(ah1, b2h[2 + nt], acc2, 0, 0, 0);
        float v0 = acc2[0] > 0.f ? acc2[0] : 0.f;
        float v1 = acc2[1] > 0.f ? acc2[1] : 0.f;
        float v2 = acc2[2] > 0.f ? acc2[2] : 0.f;
        float v3 = acc2[3] > 0.f ? acc2[3] : 0.f;
        uint2 pk;
        pk.x = pkbf(v0, v1);
        pk.y = pkbf(v2, v3);
        // stage [pix 4q+r][ch nt*16+b]; invalid pix rows hold 0 (not copied)
        short* sp = st + nt * 16 + b;
        sp[(4 * q + 0) * 32] = (short)pk.x;
        sp[(4 * q + 1) * 32] = (short)(pk.x >> 16);
        sp[(4 * q + 2) * 32] = (short)pk.y;
        sp[(4 * q + 3) * 32] = (short)(pk.y >> 16);
        pkc[nt] = pk;
      }
      __builtin_amdgcn_wave_barrier();
      if (lane < 52) {   // one coalesced 832B burst: 13 pix x 32 ch
        bf16x8 vv = *(const bf16x8*)(st + lane * 8);
        *(bf16x8*)(gb + (size_t)i * 416 + lane * 8) = vv;
      }
      if (i & 1) {       // syrk over row pair (i-1, i), frags from registers
        bf16x8 xf0 = mkfrag(pkp[0], pkc[0]);
        bf16x8 xf1 = mkfrag(pkp[1], pkc[1]);
        accT0 = __builtin_amdgcn_mfma_f32_16x16x32_bf16(xf0, xf0, accT0, 0, 0, 0);
        accT1 = __builtin_amdgcn_mfma_f32_16x16x32_bf16(xf0, xf1, accT1, 0, 0, 0);
        accT2 = __builtin_amdgcn_mfma_f32_16x16x32_bf16(xf1, xf1, accT2, 0, 0, 0);
        accS0 = __builtin_amdgcn_mfma_f32_16x16x32_bf16(ones, xf0, accS0, 0, 0, 0);
        accS1 = __builtin_amdgcn_mfma_f32_16x16x32_bf16(ones, xf1, accS1, 0, 0, 0);
      } else {
        pkp[0] = pkc[0];
        pkp[1] = pkc[1];
      }
      __builtin_amdgcn_wave_barrier();
    }
    // leftover row 12 (parity 0, held in pkp): pair with zeros
    {
      uint2 zz; zz.x = 0u; zz.y = 0u;
      bf16x8 xf0 = mkfrag(pkp[0], zz);
      bf16x8 xf1 = mkfrag(pkp[1], zz);
      accT0 = __builtin_amdgcn_mfma_f32_16x16x32_bf16(xf0, xf0, accT0, 0, 0, 0);
      accT1 = __builtin_amdgcn_mfma_f32_16x16x32_bf16(xf0, xf1, accT1, 0, 0, 0);
      accT2 = __builtin_amdgcn_mfma_f32_16x16x32_bf16(xf1, xf1, accT2, 0, 0, 0);
      accS0 = __builtin_amdgcn_mfma_f32_16x16x32_bf16(ones, xf0, accS0, 0, 0, 0);
      accS1 = __builtin_amdgcn_mfma_f32_16x16x32_bf16(ones, xf1, accS1, 0, 0, 0);
    }
  }
  // S2: all rows of accS are identical column sums; col(lane&15)=ch.
  if (q == 0) {
    s2red[w * 32 + b]      = accS0[0];
    s2red[w * 32 + 16 + b] = accS1[0];
  }
  float* redc = (float*)sb;   // wave w writes only into its own quarter
  __syncthreads();            // all sb reads done
#pragma unroll
  for (int rr = 0; rr < 4; ++rr) {
    int m = 4 * q + rr;
    redc[w * 1024 + 0   + m * 16 + b] = accT0[rr];
    redc[w * 1024 + 256 + m * 16 + b] = accT1[rr];
    redc[w * 1024 + 512 + m * 16 + b] = accT2[rr];
  }
  __syncthreads();
  for (int e = tid; e < 768; e += 256)
    parts[blockIdx.x * 800 + e] =
        redc[e] + redc[1024 + e] + redc[2048 + e] + redc[3072 + e];
  if (tid < 32)
    parts[blockIdx.x * 800 + 768 + tid] =
        s2red[tid] + s2red[32 + tid] + s2red[64 + tid] + s2red[96 + tid];
}

// Reduce C2/S2 block partials: one block per entry e in [0,800).
__global__ __launch_bounds__(256) void k_statsC(
    const float* __restrict__ parts, float* __restrict__ ws)
{
  const int e = blockIdx.x, tid = threadIdx.x;
  const int w = tid >> 6, lane = tid & 63;
  __shared__ float rs[4];
  float s = 0.f;
#pragma unroll 4
  for (int i = tid; i < 1024; i += 256) s += parts[i * 800 + e];
#pragma unroll
  for (int d = 1; d < 64; d <<= 1) s += __shfl_xor(s, d);
  if (lane == 0) rs[w] = s;
  __syncthreads();
  if (tid == 0) ws[C2R_OFF + e] = rs[0] + rs[1] + rs[2] + rs[3];
}

// BN3 finalize from S2/C2: mean=w3^T S2/N, E[y3^2]=w3^T C2 w3 /N.
__global__ __launch_bounds__(64) void k_stats3n(
    const float* __restrict__ w3, const float* __restrict__ gamma,
    const float* __restrict__ beta, float* __restrict__ ws)
{
  const int c3 = threadIdx.x;
  if (c3 >= 64) return;
  const float* C2R = ws + C2R_OFF;
  float wr[32];
#pragma unroll
  for (int k = 0; k < 32; ++k) wr[k] = w3[c3 * 32 + k];
  const float inv_n = 1.0f / (16384.0f * 169.0f);
  float msum = 0.f;
#pragma unroll
  for (int k = 0; k < 32; ++k) msum += wr[k] * C2R[768 + k];
  float e2 = 0.f;
  for (int a = 0; a < 16; ++a)
#pragma unroll
    for (int bb = 0; bb < 16; ++bb) {
      e2 += wr[a] * wr[bb] * C2R[a * 16 + bb];                  // T00
      e2 += wr[16 + a] * wr[16 + bb] * C2R[512 + a * 16 + bb];  // T11
      e2 += 2.f * wr[a] * wr[16 + bb] * C2R[256 + a * 16 + bb]; // T01
    }
  float mean = msum * inv_n;
  float var  = e2 * inv_n - mean * mean;
  float sv   = gamma[c3] * rsqrtf(var + 1e-5f);
  ws[ST3 + c3]      = sv;
  ws[ST3 + 64 + c3] = beta[c3] - mean * sv;
}

// K0: pack fc_w into the register-direct FC order:
// fcB[((p*2+h)*64 + lane)*4 + u]; lane=(q<<4)|b; jj=b; k=8q+e elements with
// c3(e) = h*32 + (e>>2)*16 + 4q + (e&3); F_orig = c3*169 + p.
__global__ __launch_bounds__(256) void k0_fcB(
    const float* __restrict__ fcw, unsigned int* __restrict__ fcB)
{
  int f = blockIdx.x * 256 + threadIdx.x;   // FCB_N = 338*256 exactly
  int u = f & 3, lane = (f >> 2) & 63, h = (f >> 8) & 1, p = f >> 9;
  int b = lane & 15, q = lane >> 4;
  unsigned lo = 0, hi = 0;
  if (b < 10) {
    int c30 = h * 32 + (u >> 1) * 16 + 4 * q + 2 * (u & 1);
    lo = f2bf(fcw[b * 10816 + c30 * 169 + p]);
    hi = f2bf(fcw[b * 10816 + (c30 + 1) * 169 + p]);
  }
  fcB[f] = lo | (hi << 16);
}

// K7: conv3 operand-swapped (A=w3 m=c3, B=a2^T n=img) + FC direct from regs.
__global__ __launch_bounds__(256) void k7_fc(
    const short* __restrict__ a2g, const float* __restrict__ w3,
    const float* __restrict__ fcb, const float* __restrict__ ws,
    float* __restrict__ out)
{
  __shared__ float redf7[1024];
  const int tid = threadIdx.x, w = tid >> 6, lane = tid & 63;
  const int b = lane & 15, q = lane >> 4;
  bf16x8 b3h[4];     // A-side: m=c3=nt*16+b, k=ch 8q+j, scaled by s3[c3]
  f32x4 c3i[4];      // C-init: rows are c3-local 4q+r -> t3[nt*16+4q+r]
#pragma unroll
  for (int nt = 0; nt < 4; ++nt) {
    float s3 = ws[ST3 + nt * 16 + b];
    bf16x8 vh;
#pragma unroll
    for (int j = 0; j < 8; ++j)
      vh[j] = (short)f2bf(w3[(nt * 16 + b) * 32 + 8 * q + j] * s3);
    b3h[nt] = vh;
#pragma unroll
    for (int r = 0; r < 4; ++r)
      c3i[nt][r] = ws[ST3 + 64 + nt * 16 + 4 * q + r];
  }
  const bf16x8* fcB = (const bf16x8*)ws;
  const short* abase = a2g + (size_t)(blockIdx.x * 16 + b) * 5408 + 8 * q;
  const int p0 = (w * 169) >> 2, p1 = ((w + 1) * 169) >> 2;
  f32x4 aF0 = {0.f, 0.f, 0.f, 0.f}, aF1 = {0.f, 0.f, 0.f, 0.f};
  bf16x8 vpre = *(const bf16x8*)(abase + p0 * 32);
  bf16x8 bw0 = fcB[(p0 * 2 + 0) * 64 + lane];
  bf16x8 bw1 = fcB[(p0 * 2 + 1) * 64 + lane];
#pragma unroll 1
  for (int p = p0; p < p1; ++p) {
    bf16x8 vc = vpre, f0 = bw0, f1 = bw1;
    if (p + 1 < p1) {
      vpre = *(const bf16x8*)(abase + (p + 1) * 32);
      bw0 = fcB[((p + 1) * 2 + 0) * 64 + lane];
      bw1 = fcB[((p + 1) * 2 + 1) * 64 + lane];
    }
    uint2 pkc[4];
#pragma unroll
    for (int nt = 0; nt < 4; ++nt) {
      f32x4 acc3 = c3i[nt];
      acc3 = __builtin_amdgcn_mfma_f32_16x16x32_bf16(b3h[nt], vc, acc3, 0, 0, 0);
      float v0 = acc3[0] > 0.f ? acc3[0] : 0.f;
      float v1 = acc3[1] > 0.f ? acc3[1] : 0.f;
      float v2 = acc3[2] > 0.f ? acc3[2] : 0.f;
      float v3 = acc3[3] > 0.f ? acc3[3] : 0.f;
      pkc[nt].x = pkbf(v0, v1);
      pkc[nt].y = pkbf(v2, v3);
    }
    aF0 = __builtin_amdgcn_mfma_f32_16x16x32_bf16(mkfrag(pkc[0], pkc[1]), f0, aF0, 0, 0, 0);
    aF1 = __builtin_amdgcn_mfma_f32_16x16x32_bf16(mkfrag(pkc[2], pkc[3]), f1, aF1, 0, 0, 0);
  }
  // FC D: col(lane&15)=jj=b, row(4q+r)=img-slot. Reduce the 4 pix-chunk waves.
#pragma unroll
  for (int r = 0; r < 4; ++r)
    redf7[w * 256 + (4 * q + r) * 16 + b] = aF0[r] + aF1[r];
  __syncthreads();
  if (tid < 160) {
    int img = tid / 10, jj = tid - img * 10;
    float s = redf7[img * 16 + jj] + redf7[256 + img * 16 + jj] +
              redf7[512 + img * 16 + jj] + redf7[768 + img * 16 + jj];
    out[(blockIdx.x * 16 + img) * 10 + jj] = s + fcb[jj];
  }
}

extern "C" void kernel_launch(void* const* d_in, const int* in_sizes, int n_in,
                              void* d_out, int out_size, void* d_ws, size_t ws_size,
                              hipStream_t stream) {
  (void)in_sizes; (void)n_in; (void)out_size; (void)ws_size;
  const float* x   = (const float*)d_in[0];
  const float* w1  = (const float*)d_in[1];
  const float* w2  = (const float*)d_in[2];
  const float* w3  = (const float*)d_in[3];
  const float* g1  = (const float*)d_in[4];
  const float* b1  = (const float*)d_in[5];
  const float* g2  = (const float*)d_in[6];
  const float* b2  = (const float*)d_in[7];
  const float* g3  = (const float*)d_in[8];
  const float* b3  = (const float*)d_in[9];
  const float* fcw = (const float*)d_in[10];
  const float* fcb = (const float*)d_in[11];
  float* out = (float*)d_out;
  float* ws  = (float*)d_ws;
  short* a2g = (short*)((char*)d_ws + A2G_BYTE);
  float* parts = ws + C2P_OFF;

  k1_xsyrk<<<1024, 256, 0, stream>>>(x, parts);
  k_stats1a<<<256, 256, 0, stream>>>(parts, ws);
  k_stats1b<<<1, 64, 0, stream>>>(w1, g1, b1, ws);
  k3_conv2_stats<<<1024, 256, 0, stream>>>(x, w1, w2, ws);
  k_stats2<<<32, 256, 0, stream>>>(g2, b2, ws, 32, P2_OFF, ST2,
                                   1.0f / (16384.0f * 169.0f));
  k5_a2<<<1024, 256, 0, stream>>>(x, w1, w2, ws, a2g, parts);
  k_statsC<<<800, 256, 0, stream>>>(parts, ws);
  k_stats3n<<<1, 64, 0, stream>>>(w3, g3, b3, ws);
  k0_fcB<<<FCB_N / 256, 256, 0, stream>>>(fcw, (unsigned int*)ws);
  k7_fc<<<1024, 256, 0, stream>>>(a2g, w3, fcb, ws, out);
}